// Round 7
// baseline (2116.646 us; speedup 1.0000x reference)
//
#include <hip/hip_runtime.h>
#include <stdint.h>

// ---------------- problem constants ----------------
#define NN     1600
#define NBEAT  200
#define FINW   299
#define HSTR   300      // padded row stride for h
#define SECW   43
#define EDG    12
#define C3     129      // 3*43 projected width
#define CM     128      // main columns (129th handled separately)
#define DEG_CAP 256     // per-destination adjacency bucket (mean 77, max~112)

#define NB_WA3   450
#define NB_INIT8 200
#define NB_SCAN  2560

#define GRUB 1024       // cooperative GRU kernel grid (4 blocks/CU -- co-resident)

// exp2/rcp-based fast activations: -log2e and -2*log2e scales folded in.
#define K1C (-1.4426950408889634f)
#define K2C (-2.8853900817779268f)

#if __has_builtin(__builtin_amdgcn_exp2f)
__device__ __forceinline__ float fexp2(float x){ return __builtin_amdgcn_exp2f(x); }
#else
__device__ __forceinline__ float fexp2(float x){ return exp2f(x); }
#endif
#if __has_builtin(__builtin_amdgcn_rcpf)
__device__ __forceinline__ float frcp(float x){ return __builtin_amdgcn_rcpf(x); }
#else
__device__ __forceinline__ float frcp(float x){ return 1.0f/x; }
#endif

__device__ __forceinline__ float sigm(float x){ return frcp(1.f + fexp2(K1C*x)); }
__device__ __forceinline__ float tanh_(float x){ return __builtin_fmaf(frcp(1.f + fexp2(K2C*x)), 2.f, -1.f); }

__device__ __forceinline__ float gate_scale(int col){
  return (col >= 64 && col < 96) ? K2C : K1C;
}

// high lane l receives v from lane l-32 (VALU permlane, no lgkm wait).
// r[0] high lane l = v[l-32]  (verified R5).
__device__ __forceinline__ float swap_lo_to_hi(float v){
#if __has_builtin(__builtin_amdgcn_permlane32_swap)
  typedef unsigned u32x2 __attribute__((ext_vector_type(2)));
  u32x2 r = __builtin_amdgcn_permlane32_swap(__float_as_uint(v), __float_as_uint(v), false, false);
  return __uint_as_float(r[0]);
#else
  return __shfl(v, (int)(threadIdx.x & 31), 64);
#endif
}

// ---------------- workspace layout (4-byte words) ----------------
constexpr size_t OFF_H    = 0;                                   // 1600*300
constexpr size_t OFF_WA3  = OFF_H    + (size_t)NN*HSTR;          // 12*299*128
constexpr size_t OFF_WA3X = OFF_WA3  + (size_t)EDG*FINW*CM;      // 12*299
constexpr size_t OFF_B3   = OFF_WA3X + (size_t)EDG*FINW;         // 132
constexpr size_t OFF_MST  = OFF_B3   + 132;                      // 12*1600*128
constexpr size_t OFF_MSTX = OFF_MST  + (size_t)EDG*NN*CM;        // 12*1600
constexpr size_t OFF_M3   = OFF_MSTX + (size_t)EDG*NN;           // 12*1600*128
constexpr size_t OFF_M3X  = OFF_M3   + (size_t)EDG*NN*CM;        // 12*1600
constexpr size_t OFF_CUR  = OFF_M3X  + (size_t)EDG*NN;           // 1600 ints
constexpr size_t OFF_BAR  = OFF_CUR  + NN;                       // 4 ints: [0]=arrive,[1]=gen
constexpr size_t OFF_ADJR = OFF_BAR  + 4;                        // 1600*256 ints
constexpr size_t OFF_XW   = OFF_ADJR + (size_t)NN*DEG_CAP;       // 2*128*200
constexpr size_t OFF_RNN0 = OFF_XW   + (size_t)2*NBEAT*128;      // 200*64
constexpr size_t OFF_RNN1 = OFF_RNN0 + (size_t)NBEAT*64;         // 200*64

// ---------------- explicit device-scope grid barrier (sense-generation) ----------------
// Cross-XCD safe by construction: syncthreads drains each wave's stores to its
// L2; lead-thread __threadfence() (agent fence) writes back L2; acq_rel agent
// atomics on the counters; acquire fence on exit invalidates L1/L2 before any
// thread reads other blocks' data. Does NOT rely on OCKL grid.sync internals.
__device__ __forceinline__ void grid_barrier(int* bar, int* gen, int nblk){
  __syncthreads();
  if (threadIdx.x == 0){
    __threadfence();   // agent-scope release: L2 writeback of this block's data
    int g = __hip_atomic_load(gen, __ATOMIC_RELAXED, __HIP_MEMORY_SCOPE_AGENT);
    int a = __hip_atomic_fetch_add(bar, 1, __ATOMIC_ACQ_REL, __HIP_MEMORY_SCOPE_AGENT);
    if (a == nblk-1){
      __hip_atomic_store(bar, 0,   __ATOMIC_RELAXED, __HIP_MEMORY_SCOPE_AGENT);
      __hip_atomic_store(gen, g+1, __ATOMIC_RELEASE, __HIP_MEMORY_SCOPE_AGENT);
    } else {
      while (__hip_atomic_load(gen, __ATOMIC_RELAXED, __HIP_MEMORY_SCOPE_AGENT) == g){
        __builtin_amdgcn_s_sleep(2);
      }
    }
    __threadfence();   // agent-scope acquire: invalidate L1/L2 before reads
  }
  __syncthreads();
}

// ---------------- fused setup: wa3(8-row GEMM) | init8 | adj-scan ----------------
__global__ __launch_bounds__(192) void k_setup(
    const float* wa, const float* ba, const float* wz, const float* wr, const float* wh,
    const float* note, const float* pv, const float* w_style, const float* b_style,
    const float* w1, const float* b1, const float* w2, const float* b2,
    const float* edges, float* ws, float* dout){
  int blk = blockIdx.x;
  int t = threadIdx.x;
  __shared__ __align__(16) float smem[2392];
  if (blk < NB_WA3){
    float* lrow = smem;            // 299*8
    int base = blk*8;
    for (int x=t; x<8*299; x+=192){
      int r = x & 7, s = x >> 3;
      int R = base + r;
      float v = 0.f;
      if (R < 3588)       v = wa[(size_t)R*FINW + s];
      else if (R == 3588) v = ba[s];
      lrow[s*8 + r] = v;
    }
    __syncthreads();
    if (t < C3){
      const float* Wp; int cc;
      if (t<43){Wp=wz; cc=t;} else if (t<86){Wp=wr; cc=t-43;} else {Wp=wh; cc=t-86;}
      float acc[8];
      #pragma unroll
      for (int r=0;r<8;r++) acc[r]=0.f;
      for (int s=0;s<FINW;s++){
        float w = Wp[s*43+cc];
        float4 lo = *(const float4*)&lrow[s*8];
        float4 hi = *(const float4*)&lrow[s*8+4];
        acc[0]+=lo.x*w; acc[1]+=lo.y*w; acc[2]+=lo.z*w; acc[3]+=lo.w*w;
        acc[4]+=hi.x*w; acc[5]+=hi.y*w; acc[6]+=hi.z*w; acc[7]+=hi.w*w;
      }
      #pragma unroll
      for (int r=0;r<8;r++){
        int R = base + r;
        if (R < 3588){
          if (t<CM) ws[OFF_WA3 + (size_t)R*CM + t] = acc[r];
          else      ws[OFF_WA3X + R]               = acc[r];
        } else if (R == 3588){
          ws[OFF_B3 + t] = acc[r];
        }
      }
    }
  } else if (blk < NB_WA3 + NB_INIT8){
    float* ln    = smem;           // 1024
    float* lh1   = smem + 1024;    // 512
    float* lo    = smem + 1536;    // 88
    float* lperf = smem + 1624;    // 64
    int i0 = (blk - NB_WA3)*8;
    for (int x=t; x<8*128; x+=192){
      int r = x >> 7, k = x & 127;
      ln[k*8 + r] = note[(size_t)(i0+r)*128 + k];
    }
    if (t>=64 && t<128){
      int u=t-64;
      float acc=b_style[u];
      for (int k=0;k<16;k++) acc += pv[k]*w_style[k*64+u];
      lperf[u]=fmaxf(acc,0.f);
    }
    __syncthreads();
    if (t<64){
      float acc[8];
      #pragma unroll
      for (int r=0;r<8;r++) acc[r]=b1[t];
      for (int k=0;k<128;k++){
        float w = w1[k*64+t];
        float4 a = *(const float4*)&ln[k*8];
        float4 b = *(const float4*)&ln[k*8+4];
        acc[0]+=a.x*w; acc[1]+=a.y*w; acc[2]+=a.z*w; acc[3]+=a.w*w;
        acc[4]+=b.x*w; acc[5]+=b.y*w; acc[6]+=b.z*w; acc[7]+=b.w*w;
      }
      #pragma unroll
      for (int r=0;r<8;r++) lh1[t*8+r]=fmaxf(acc[r],0.f);
    }
    __syncthreads();
    if (t<88){
      int r = t & 7, c = t >> 3;
      float acc=b2[c];
      for (int k=0;k<64;k++) acc += lh1[k*8+r]*w2[k*11+c];
      lo[r*11+c]=acc;
      dout[17600 + (size_t)(i0+r)*11 + c] = acc;
    }
    __syncthreads();
    #pragma unroll
    for (int r=0;r<8;r++){
      for (int c=t;c<FINW;c+=192){
        float v;
        if (c<128)      v=ln[c*8+r];
        else if (c<192) v=lperf[c-128];
        else if (c<256) v=0.f;
        else if (c<267) v=lo[r*11+(c-256)];
        else            v=0.f;
        ws[OFF_H + (size_t)(i0+r)*HSTR + c]=v;
      }
    }
  } else {
    int* cur  = (int*)(ws + OFF_CUR);
    int* adjr = (int*)(ws + OFF_ADJR);
    const uint4* p = (const uint4*)edges;
    const unsigned int nvec = 7680000u;
    const unsigned int stride = (unsigned int)NB_SCAN*192u;
    unsigned int v0 = (unsigned int)(blk - NB_WA3 - NB_INIT8)*192u + t;
    for (unsigned int b0 = v0; b0 < nvec; b0 += 4u*stride){
      unsigned int v1=b0+stride, v2=b0+2u*stride, v3=b0+3u*stride;
      bool g1=v1<nvec, g2=v2<nvec, g3=v3<nvec;
      uint4 w0 = p[b0];
      uint4 w1v = g1 ? p[v1] : make_uint4(0,0,0,0);
      uint4 w2v = g2 ? p[v2] : make_uint4(0,0,0,0);
      uint4 w3v = g3 ? p[v3] : make_uint4(0,0,0,0);
      uint4 wv[4] = {w0,w1v,w2v,w3v};
      unsigned int vv[4] = {b0,v1,v2,v3};
      #pragma unroll
      for (int u=0; u<4; u++){
        uint4 w = wv[u];
        if ((w.x|w.y|w.z|w.w)==0u) continue;
        unsigned int base = vv[u]*4u;
        unsigned int arr[4]={w.x,w.y,w.z,w.w};
        #pragma unroll
        for (int q=0;q<4;q++){
          if (arr[q]){
            unsigned int idx=base+q;
            unsigned int j=idx%1600u;
            int slot=atomicAdd(&cur[j],1);
            if (slot<DEG_CAP) adjr[j*DEG_CAP + slot]=(int)(idx/1600u);
          }
        }
      }
    }
  }
}

// ---------------- static message part + M3(h0) (once per seq-iter) ----------------
__global__ void k_mstat(float* ws, int dmain){
  int e = blockIdx.y; int i0 = blockIdx.x*8;
  int t = threadIdx.x;
  __shared__ float lh[8][256];
  __shared__ float lh2[8][44];
  const float* h = ws + OFF_H;
  for (int x=t; x<512; x+=64){
    int r = x>>6, dq = x&63;
    ((float4*)&lh[r][0])[dq] = ((const float4*)(h + (size_t)(i0+r)*HSTR))[dq];
  }
  for (int x=t; x<88; x+=64){
    int r = x/11, dq = x-r*11;
    ((float4*)&lh2[r][0])[dq] = ((const float4*)(h + (size_t)(i0+r)*HSTR + 256))[dq];
  }
  __syncthreads();
  const float* wm = ws + OFF_WA3 + (size_t)e*FINW*CM;
  int c0 = 2*t;
  float acc[8][2];
  #pragma unroll
  for (int r=0;r<8;r++){acc[r][0]=0.f;acc[r][1]=0.f;}
  for (int d=0; d<dmain; d+=4){
    float4 hv[8];
    #pragma unroll
    for (int r=0;r<8;r++) hv[r] = *(const float4*)&lh[r][d];
    #pragma unroll
    for (int dd=0;dd<4;dd++){
      float2 w = *(const float2*)(wm + (size_t)(d+dd)*CM + c0);
      #pragma unroll
      for (int r=0;r<8;r++){
        float hvv = ((const float*)&hv[r])[dd];
        acc[r][0] += hvv*w.x; acc[r][1] += hvv*w.y;
      }
    }
  }
  float* mst = ws + OFF_MST + ((size_t)e*NN + i0)*CM;
  #pragma unroll
  for (int r=0;r<8;r++) *(float2*)(mst + (size_t)r*CM + c0) = make_float2(acc[r][0],acc[r][1]);
  const float* wd = wm + (size_t)256*CM;
  for (int d=0; d<SECW; d++){
    float2 w = *(const float2*)(wd + (size_t)d*CM + c0);
    #pragma unroll
    for (int r=0;r<8;r++){
      float hvv = lh2[r][d];
      acc[r][0] += hvv*w.x; acc[r][1] += hvv*w.y;
    }
  }
  float* m3 = ws + OFF_M3 + ((size_t)e*NN + i0)*CM;
  #pragma unroll
  for (int r=0;r<8;r++) *(float2*)(m3 + (size_t)r*CM + c0) = make_float2(acc[r][0],acc[r][1]);
  if (t<8){
    const float* wx = ws + OFF_WA3X + (size_t)e*FINW;
    float a=0.f;
    for (int d=0; d<dmain; d++) a += lh[t][d]*wx[d];
    ws[OFF_MSTX + (size_t)e*NN + i0 + t] = a;
    for (int d=0; d<SECW; d++) a += lh2[t][d]*wx[256+d];
    ws[OFF_M3X + (size_t)e*NN + i0 + t] = a;
  }
}

// ---------------- GRU phase bodies (shared by coop kernel and fallback) ----------------
__device__ __forceinline__ void agg_gru_body(float* ws, const float* uz, const float* ur,
                                             const float* uh, float* sm, int j){
  int t = threadIdx.x;   // 128
  float* lpre = sm;              // 132
  float* lhs  = sm + 132;        // 43
  float* lrh  = sm + 176;        // 43
  int*   ladj = (int*)(sm + 224); // 256 ints
  float* h = ws + OFF_H;
  const int* cur =(const int*)(ws+OFF_CUR);
  const int* adjr=(const int*)(ws+OFF_ADJR) + (size_t)j*DEG_CAP;
  int cnt = cur[j]; if (cnt>DEG_CAP) cnt=DEG_CAP;
  for (int k=t;k<cnt;k+=128) ladj[k]=adjr[k];
  if (t<SECW) lhs[t] = h[(size_t)j*HSTR + 256 + t];
  __syncthreads();
  const float* M3=ws+OFF_M3; const float* M3X=ws+OFF_M3X;
  float a0 = ws[OFF_B3 + t];
  float ax = (t==0)? ws[OFF_B3+128] : 0.f;
  float p1=0.f,p2=0.f,p3=0.f,p4=0.f,p5=0.f,p6=0.f,p7=0.f;
  int k=0;
  for (; k+8<=cnt; k+=8){
    int r0=ladj[k],r1=ladj[k+1],r2=ladj[k+2],r3=ladj[k+3];
    int r4=ladj[k+4],r5=ladj[k+5],r6=ladj[k+6],r7=ladj[k+7];
    a0 += M3[(size_t)r0*CM+t];
    p1 += M3[(size_t)r1*CM+t];
    p2 += M3[(size_t)r2*CM+t];
    p3 += M3[(size_t)r3*CM+t];
    p4 += M3[(size_t)r4*CM+t];
    p5 += M3[(size_t)r5*CM+t];
    p6 += M3[(size_t)r6*CM+t];
    p7 += M3[(size_t)r7*CM+t];
    if (t==0) ax += ((M3X[r0]+M3X[r1])+(M3X[r2]+M3X[r3]))
                  + ((M3X[r4]+M3X[r5])+(M3X[r6]+M3X[r7]));
  }
  for (; k<cnt; k++){ int r=ladj[k]; a0+=M3[(size_t)r*CM+t]; if(t==0) ax+=M3X[r]; }
  a0 += ((p1+p2)+(p3+p4)) + ((p5+p6)+p7);
  lpre[t]=a0; if (t==0) lpre[128]=ax;
  __syncthreads();
  float z=0.f;
  if (t<SECW){
    float az=lpre[t], ar=lpre[43+t];
    for (int d=0;d<SECW;d++){ float hv=lhs[d]; az+=hv*uz[d*43+t]; ar+=hv*ur[d*43+t]; }
    z=sigm(az);
    float r=sigm(ar);
    lrh[t]=r*lhs[t];
  }
  __syncthreads();
  if (t<SECW){
    float ah=lpre[86+t];
    for (int d=0;d<SECW;d++) ah += lrh[d]*uh[d*43+t];
    float cand=tanh_(ah);
    h[(size_t)j*HSTR+256+t] = (1.f-z)*lhs[t] + z*cand;
  }
}

__device__ __forceinline__ void m3dyn_body(float* ws, float* sm, int u){
  int e = u % EDG, i0 = (u / EDG) * 8;
  int t = threadIdx.x & 63;
  float* lhs = sm + (threadIdx.x >> 6) * 352;   // 8*44 per half
  const float* h = ws + OFF_H;
  for (int x=t; x<8*43; x+=64){ int r=x/43, d=x-r*43; lhs[r*44+d]=h[(size_t)(i0+r)*HSTR+256+d]; }
  __syncthreads();
  const float* wd  = ws + OFF_WA3 + ((size_t)e*FINW+256)*CM;
  const float* mst = ws + OFF_MST + ((size_t)e*NN+i0)*CM;
  int c0=2*t;
  float acc[8][2];
  #pragma unroll
  for (int r=0;r<8;r++){ float2 m=*(const float2*)(mst+(size_t)r*CM+c0); acc[r][0]=m.x; acc[r][1]=m.y; }
  for (int d=0; d<43; d++){
    float2 w=*(const float2*)(wd + (size_t)d*CM + c0);
    #pragma unroll
    for (int r=0;r<8;r++){ float hv=lhs[r*44+d]; acc[r][0]+=hv*w.x; acc[r][1]+=hv*w.y; }
  }
  float* m3 = ws + OFF_M3 + ((size_t)e*NN+i0)*CM;
  #pragma unroll
  for (int r=0;r<8;r++) *(float2*)(m3+(size_t)r*CM+c0)=make_float2(acc[r][0],acc[r][1]);
  if (t<8){
    float a = ws[OFF_MSTX + (size_t)e*NN+i0+t];
    const float* wx = ws + OFF_WA3X + (size_t)e*FINW + 256;
    for (int d=0;d<43;d++) a += lhs[t*44+d]*wx[d];
    ws[OFF_M3X + (size_t)e*NN+i0+t]=a;
  }
}

// ---------------- cooperative GRU phase: agg,(m3dyn,agg)x2 in ONE launch ----------------
__global__ __launch_bounds__(128) void k_gru6(float* ws, const float* uz, const float* ur,
                                              const float* uh){
  int* bar = (int*)(ws + OFF_BAR);
  int* gen = bar + 1;
  __shared__ __align__(16) float sm[704];
  #pragma unroll 1
  for (int ph=0; ph<3; ph++){
    for (int j = blockIdx.x; j < NN; j += GRUB){
      agg_gru_body(ws, uz, ur, uh, sm, j);
      __syncthreads();
    }
    if (ph < 2){
      grid_barrier(bar, gen, GRUB);
      for (int u = blockIdx.x*2 + (int)(threadIdx.x>>6); u < EDG*NBEAT; u += 2*GRUB){
        m3dyn_body(ws, sm, u);
        __syncthreads();
      }
      grid_barrier(bar, gen, GRUB);
    }
  }
}

// ---------------- fallback separate kernels (if cooperative launch unsupported) ----
__global__ __launch_bounds__(128) void k_agg_gru_sep(float* ws, const float* uz,
                                                     const float* ur, const float* uh){
  __shared__ __align__(16) float sm[704];
  agg_gru_body(ws, uz, ur, uh, sm, blockIdx.x);
}
__global__ __launch_bounds__(128) void k_m3dyn_sep(float* ws){
  __shared__ __align__(16) float sm[704];
  m3dyn_body(ws, sm, blockIdx.x*2 + (int)(threadIdx.x>>6));
}

// ---------------- beat attention + layer-0 LSTM input projection (fused) ----------------
__global__ void k_attn_xw(float* ws, const float* mw, const float* mb, const float* mc,
                          const float* bw, const float* bb, const float* bc,
                          const float* res,
                          const float* w0f, const float* bia0f,
                          const float* w0b, const float* bia0b, float* xw){
  int b=blockIdx.x, t=threadIdx.x;  // 128 threads
  float* h=ws+OFF_H;
  __shared__ float sm[8][8];
  __shared__ float wgt[8][8];
  __shared__ float sb[8];
  __shared__ float wb_[8];
  __shared__ float lb[52];
  int n=t>>3, hh=t&7;
  if (t<64){
    const float* mrow = h + (size_t)(b*8+n)*HSTR + 267;
    float sim=0.f;
    for (int d=0;d<4;d++){
      int c=hh*4+d;
      float acc=mb[c];
      for (int k=0;k<32;k++) acc += mrow[k]*mw[k*32+c];
      sim += tanh_(acc)*mc[c];
    }
    sm[n][hh]=sim;
  }
  if (t<8){
    const float* irow = h + (size_t)(b*8+t)*HSTR + 256;
    float sim=0.f;
    for (int d=0;d<11;d++){
      float acc=bb[d];
      for (int k=0;k<11;k++) acc += irow[k]*bw[k*11+d];
      sim += tanh_(acc)*bc[d];
    }
    sb[t]=sim;
  }
  __syncthreads();
  if (t<64){
    float m=-1e30f;
    for (int q=0;q<8;q++) m=fmaxf(m, sm[q][hh]);
    float Z=0.f;
    for (int q=0;q<8;q++) Z+=__expf(sm[q][hh]-m);
    wgt[n][hh]=__expf(sm[n][hh]-m)/Z;
  }
  if (t<8){
    float m=-1e30f;
    for (int q=0;q<8;q++) m=fmaxf(m, sb[q]);
    float Z=0.f;
    for (int q=0;q<8;q++) Z+=__expf(sb[q]-m);
    wb_[t]=__expf(sb[t]-m)/Z;
  }
  __syncthreads();
  if (t<32){
    int hh2=t>>2;
    float acc=0.f;
    for (int q=0;q<8;q++) acc += wgt[q][hh2]* h[(size_t)(b*8+q)*HSTR + 267 + t];
    lb[11+t]=acc;
  }
  if (t<11){
    float acc=0.f;
    for (int q=0;q<8;q++) acc += wb_[q]* h[(size_t)(b*8+q)*HSTR + 256 + t];
    lb[t]=acc;
  }
  if (t<8) lb[43+t]=res[b*8+t];
  __syncthreads();
  float acc0=bia0f[t], acc1=bia0b[t];
  for (int k=0;k<51;k++){
    float v=lb[k];
    acc0 += v*w0f[t*51+k];
    acc1 += v*w0b[t*51+k];
  }
  float sc = gate_scale(t);
  xw[((size_t)t)*NBEAT + b]       = acc0*sc;
  xw[((size_t)(128+t))*NBEAT + b] = acc1*sc;
}

// ---------------- LSTM layer-1 input projection (transposed + pre-scaled out) ----------------
__global__ void k_xw(const float* inp, int din, const float* wf, const float* bf_,
                     const float* wb, const float* bb_, float* xw){
  int bid=blockIdx.x; int tt=bid>>1, dir=bid&1;
  const float* w = dir? wb:wf; const float* bia = dir? bb_:bf_;
  __shared__ float rowl[64];
  int t=threadIdx.x;   // 128 threads
  if (t<din) rowl[t]=inp[(size_t)tt*din+t];
  __syncthreads();
  float acc=bia[t];
  for (int k=0;k<din;k++) acc += rowl[k]*w[t*din+k];
  xw[((size_t)(dir*128 + t))*NBEAT + tt] = acc*gate_scale(t);
}

// ---------------- LSTM scan, latency-optimized ----------------
template<int DIR>
__device__ __forceinline__ void chunk8(int c, const float4& A0, const float4& A1,
    const float4& B0, const float4& B1,
    float* hu, float& creg, const float4* rA, const float4* rB,
    float cb1, float cb0, int l, float* out){
  float cxA[8] = {A0.x,A0.y,A0.z,A0.w,A1.x,A1.y,A1.z,A1.w};
  float cxB[8] = {B0.x,B0.y,B0.z,B0.w,B1.x,B1.y,B1.z,B1.w};
  float hst[8];
  #pragma unroll
  for (int u=0; u<8; u++){
    const int e = DIR ? (7-u) : u;
    float av[8], bv[8];
    #pragma unroll
    for (int q=0; q<8; q++){
      av[q] = hu[4*q+0]*rA[q].x + hu[4*q+1]*rA[q].y + hu[4*q+2]*rA[q].z + hu[4*q+3]*rA[q].w;
      bv[q] = hu[4*q+0]*rB[q].x + hu[4*q+1]*rB[q].y + hu[4*q+2]*rB[q].z + hu[4*q+3]*rB[q].w;
    }
    float accA = cxA[e] + (((av[0]+av[1])+(av[2]+av[3])) + ((av[4]+av[5])+(av[6]+av[7])));
    float accB = cxB[e] + (((bv[0]+bv[1])+(bv[2]+bv[3])) + ((bv[4]+bv[5])+(bv[6]+bv[7])));
    float pA  = frcp(1.f + fexp2(accA));            // sigm(i) low | sigm(f) high
    float rBv = frcp(1.f + fexp2(accB));
    float pB  = __builtin_fmaf(rBv, cb1, cb0);      // K2C*tanh(g) low | sigm(o) high
    float prod = pA * pB;                           // K2C*(i*g) in low lanes
    float prodIn = swap_lo_to_hi(prod);             // high lane l <- prod[l-32] (VALU)
    creg = __builtin_fmaf(pA, creg, prodIn);        // scaled c update (valid high lanes)
    float T = __builtin_fmaf(frcp(1.f + fexp2(creg)), 2.f, -1.f);  // tanh(c)
    float hnew = pB * T;                            // sigm(o)*tanh(c) (valid high lanes)
    hst[u] = hnew;
    #pragma unroll
    for (int d=0; d<32; d++)                        // broadcast h -> SGPRs for next step
      hu[d] = __uint_as_float(__builtin_amdgcn_readlane(__float_as_uint(hnew), 32+d));
  }
  if (l >= 32){
    int j = l - 32;
    #pragma unroll
    for (int u=0; u<8; u++){
      int s = c*8 + u;
      int tt = DIR ? (199 - s) : s;
      out[(size_t)tt*64 + DIR*32 + j] = hst[u];
    }
  }
}

template<int DIR>
__device__ __forceinline__ void lstm_scan(const float* xwT, const float* whh, float* out){
  const int l = threadIdx.x;
  const float sB = (l < 32) ? K2C : K1C;
  float4 rA[8], rB[8];
  #pragma unroll
  for (int q=0; q<8; q++){
    float4 a = *(const float4*)&whh[l*32 + q*4];
    float4 b = *(const float4*)&whh[(l+64)*32 + q*4];
    rA[q] = make_float4(a.x*K1C, a.y*K1C, a.z*K1C, a.w*K1C);
    rB[q] = make_float4(b.x*sB,  b.y*sB,  b.z*sB,  b.w*sB);
  }
  const float cb1 = (l < 32) ? (2.f*K2C) : 1.f;
  const float cb0 = (l < 32) ? (-K2C)    : 0.f;
  const float* xA = xwT + ((size_t)DIR*128 + l)*NBEAT;
  const float* xB = xwT + ((size_t)DIR*128 + 64 + l)*NBEAT;
  float hu[32];
  #pragma unroll
  for (int d=0; d<32; d++) hu[d] = 0.f;
  float creg = 0.f;
  float4 A0,A1,B0,B1, P0,P1,Q0,Q1;
#define LOADC(cidx, a0,a1,b0,b1) do {               \
    int _b = DIR ? (192 - (cidx)*8) : ((cidx)*8);   \
    a0 = *(const float4*)&xA[_b];                   \
    a1 = *(const float4*)&xA[_b+4];                 \
    b0 = *(const float4*)&xB[_b];                   \
    b1 = *(const float4*)&xB[_b+4];                 \
  } while(0)
  LOADC(0, A0,A1,B0,B1);
  for (int cc=0; cc<12; cc++){
    int c0 = 2*cc;
    LOADC(c0+1, P0,P1,Q0,Q1);
    chunk8<DIR>(c0,   A0,A1,B0,B1, hu, creg, rA, rB, cb1, cb0, l, out);
    LOADC(c0+2, A0,A1,B0,B1);
    chunk8<DIR>(c0+1, P0,P1,Q0,Q1, hu, creg, rA, rB, cb1, cb0, l, out);
  }
  chunk8<DIR>(24, A0,A1,B0,B1, hu, creg, rA, rB, cb1, cb0, l, out);
#undef LOADC
}

__global__ __launch_bounds__(64,1) void k_scan(const float* xwT, const float* whh_f,
                                               const float* whh_b, float* out){
  if (blockIdx.x == 0) lstm_scan<0>(xwT, whh_f, out);
  else                 lstm_scan<1>(xwT, whh_b, out);
}

// ---------------- fc head + final_out + h update (tempo fused) ----------------
__global__ void k_fc(float* ws, const int* bn, const float* w1, const float* b1,
                     const float* w2, const float* b2,
                     const float* wt, const float* bt, float* dout, int it){
  int i=blockIdx.x, t=threadIdx.x;   // 64 threads
  __shared__ float row[FINW];
  __shared__ float hid[32];
  __shared__ float fo[11];
  float* h=ws+OFF_H;
  int b = bn[i];
  const float* rnn = ws+OFF_RNN1;
  for (int c=t;c<FINW;c+=64){
    float v;
    if (c>=192 && c<256){ v=rnn[(size_t)b*64 + c-192]; h[(size_t)i*HSTR+c]=v; }
    else v=h[(size_t)i*HSTR+c];
    row[c]=v;
  }
  float tv = rnn[(size_t)b*64 + t]*wt[t];
  #pragma unroll
  for (int off=32; off; off>>=1) tv += __shfl_xor(tv, off, 64);
  __syncthreads();
  if (t<32){
    float acc=b1[t];
    for (int k=0;k<FINW;k++) acc += row[k]*w1[k*32+t];
    hid[t]=fmaxf(acc,0.f);
  }
  __syncthreads();
  if (t<10){
    float acc=b2[t];
    for (int m=0;m<32;m++) acc += hid[m]*w2[m*10+t];
    fo[1+t]=acc;
  }
  if (t==0) fo[0]=tv + bt[0];
  __syncthreads();
  if (t<11){
    float v=fo[t];
    h[(size_t)i*HSTR+256+t]=v;
    dout[(size_t)(2+it)*17600 + i*11 + t]=v;
    if (it==1) dout[i*11+t]=v;
  }
}

// ---------------- launcher ----------------
extern "C" void kernel_launch(void* const* d_in, const int* in_sizes, int n_in,
                              void* d_out, int out_size, void* d_ws, size_t ws_size,
                              hipStream_t stream){
  (void)in_sizes; (void)n_in; (void)out_size; (void)ws_size;
  float* ws=(float*)d_ws;
  const float* note    =(const float*)d_in[0];
  const float* pv      =(const float*)d_in[1];
  const float* res     =(const float*)d_in[2];
  const float* edges   =(const float*)d_in[3];
  const int*   bn      =(const int*)d_in[4];
  const float* w_style =(const float*)d_in[5];
  const float* b_style =(const float*)d_in[6];
  const float* w_init1 =(const float*)d_in[7];
  const float* b_init1 =(const float*)d_in[8];
  const float* w_init2 =(const float*)d_in[9];
  const float* b_init2 =(const float*)d_in[10];
  const float* gg_wa   =(const float*)d_in[11];
  const float* gg_ba   =(const float*)d_in[12];
  const float* gg_wz   =(const float*)d_in[13];
  const float* gg_wr   =(const float*)d_in[14];
  const float* gg_wh   =(const float*)d_in[15];
  const float* gg_uz   =(const float*)d_in[16];
  const float* gg_ur   =(const float*)d_in[17];
  const float* gg_uh   =(const float*)d_in[18];
  const float* abw     =(const float*)d_in[19];
  const float* abb     =(const float*)d_in[20];
  const float* abc     =(const float*)d_in[21];
  const float* amw     =(const float*)d_in[22];
  const float* amb     =(const float*)d_in[23];
  const float* amc     =(const float*)d_in[24];
  const float* wih0f   =(const float*)d_in[25];
  const float* whh0f   =(const float*)d_in[26];
  const float* b0f     =(const float*)d_in[27];
  const float* wih0b   =(const float*)d_in[28];
  const float* whh0b   =(const float*)d_in[29];
  const float* b0b     =(const float*)d_in[30];
  const float* wih1f   =(const float*)d_in[31];
  const float* whh1f   =(const float*)d_in[32];
  const float* b1f     =(const float*)d_in[33];
  const float* wih1b   =(const float*)d_in[34];
  const float* whh1b   =(const float*)d_in[35];
  const float* b1b     =(const float*)d_in[36];
  const float* w_tempo =(const float*)d_in[37];
  const float* b_tempo =(const float*)d_in[38];
  const float* w_fc1   =(const float*)d_in[39];
  const float* b_fc1   =(const float*)d_in[40];
  const float* w_fc2   =(const float*)d_in[41];
  const float* b_fc2   =(const float*)d_in[42];
  float* dout=(float*)d_out;

  hipMemsetAsync(ws+OFF_CUR, 0, (NN+4)*sizeof(int), stream);   // cur + barrier words
  k_setup<<<NB_WA3+NB_INIT8+NB_SCAN,192,0,stream>>>(
      gg_wa,gg_ba,gg_wz,gg_wr,gg_wh,
      note,pv,w_style,b_style,w_init1,b_init1,w_init2,b_init2,
      edges,ws,dout);

  for (int it=0; it<2; it++){
    k_mstat<<<dim3(200,12),64,0,stream>>>(ws, it==0 ? 192 : 256);   // also emits M3(h0)
    {
      void* cargs[4] = { (void*)&ws, (void*)&gg_uz, (void*)&gg_ur, (void*)&gg_uh };
      hipError_t ce = hipLaunchCooperativeKernel((const void*)k_gru6, dim3(GRUB),
                                                 dim3(128), cargs, 0, stream);
      if (ce != hipSuccess){
        // fallback: proven 5-dispatch sequence
        k_agg_gru_sep<<<NN,128,0,stream>>>(ws,gg_uz,gg_ur,gg_uh);
        for (int g=1; g<3; g++){
          k_m3dyn_sep<<<EDG*NBEAT/2,128,0,stream>>>(ws);
          k_agg_gru_sep<<<NN,128,0,stream>>>(ws,gg_uz,gg_ur,gg_uh);
        }
      }
    }
    k_attn_xw<<<NBEAT,128,0,stream>>>(ws,amw,amb,amc,abw,abb,abc,res,
                                      wih0f,b0f,wih0b,b0b,ws+OFF_XW);
    k_scan<<<2,64,0,stream>>>(ws+OFF_XW,whh0f,whh0b,ws+OFF_RNN0);
    k_xw<<<2*NBEAT,128,0,stream>>>(ws+OFF_RNN0,64,wih1f,b1f,wih1b,b1b,ws+OFF_XW);
    k_scan<<<2,64,0,stream>>>(ws+OFF_XW,whh1f,whh1b,ws+OFF_RNN1);
    k_fc<<<NN,64,0,stream>>>(ws,bn,w_fc1,b_fc1,w_fc2,b_fc2,w_tempo,b_tempo,dout,it);
  }
}

// Round 8
// 1732.419 us; speedup vs baseline: 1.2218x; 1.2218x over previous
//
#include <hip/hip_runtime.h>
#include <stdint.h>

// ---------------- problem constants ----------------
#define NN     1600
#define NBEAT  200
#define FINW   299
#define HSTR   300      // padded row stride for h
#define SECW   43
#define EDG    12
#define C3     129      // 3*43 projected width
#define CM     128      // main columns (129th handled separately)
#define DEG_CAP 256     // per-destination adjacency bucket (mean 77, max~112)

// fused-setup block ranges (all 192-thread blocks). ROLES FIRST (R2 config).
#define NB_WA3   450
#define NB_INIT8 200
#define NB_SCAN  2560

// exp2/rcp-based fast activations: -log2e and -2*log2e scales folded in.
#define K1C (-1.4426950408889634f)
#define K2C (-2.8853900817779268f)

#if __has_builtin(__builtin_amdgcn_exp2f)
__device__ __forceinline__ float fexp2(float x){ return __builtin_amdgcn_exp2f(x); }
#else
__device__ __forceinline__ float fexp2(float x){ return exp2f(x); }
#endif
#if __has_builtin(__builtin_amdgcn_rcpf)
__device__ __forceinline__ float frcp(float x){ return __builtin_amdgcn_rcpf(x); }
#else
__device__ __forceinline__ float frcp(float x){ return 1.0f/x; }
#endif

__device__ __forceinline__ float sigm(float x){ return frcp(1.f + fexp2(K1C*x)); }
__device__ __forceinline__ float tanh_(float x){ return __builtin_fmaf(frcp(1.f + fexp2(K2C*x)), 2.f, -1.f); }

__device__ __forceinline__ float gate_scale(int col){
  return (col >= 64 && col < 96) ? K2C : K1C;
}

// high lane l receives v from lane l-32 (VALU permlane, no lgkm wait).
// r[0] high lane l = v[l-32]  (verified R5; R4 bug was r[1]).
__device__ __forceinline__ float swap_lo_to_hi(float v){
#if __has_builtin(__builtin_amdgcn_permlane32_swap)
  typedef unsigned u32x2 __attribute__((ext_vector_type(2)));
  u32x2 r = __builtin_amdgcn_permlane32_swap(__float_as_uint(v), __float_as_uint(v), false, false);
  return __uint_as_float(r[0]);
#else
  return __shfl(v, (int)(threadIdx.x & 31), 64);
#endif
}

// ---------------- workspace layout (4-byte words) ----------------
constexpr size_t OFF_H    = 0;                                   // 1600*300
constexpr size_t OFF_WA3  = OFF_H    + (size_t)NN*HSTR;          // 12*299*128
constexpr size_t OFF_WA3X = OFF_WA3  + (size_t)EDG*FINW*CM;      // 12*299
constexpr size_t OFF_B3   = OFF_WA3X + (size_t)EDG*FINW;         // 132
constexpr size_t OFF_MST  = OFF_B3   + 132;                      // 12*1600*128
constexpr size_t OFF_MSTX = OFF_MST  + (size_t)EDG*NN*CM;        // 12*1600
constexpr size_t OFF_M3   = OFF_MSTX + (size_t)EDG*NN;           // 12*1600*128
constexpr size_t OFF_M3X  = OFF_M3   + (size_t)EDG*NN*CM;        // 12*1600
constexpr size_t OFF_CUR  = OFF_M3X  + (size_t)EDG*NN;           // 1600 ints
constexpr size_t OFF_ADJR = OFF_CUR  + NN;                       // 1600*256 ints
constexpr size_t OFF_XW   = OFF_ADJR + (size_t)NN*DEG_CAP;       // 2*128*200 (transposed, pre-scaled)
constexpr size_t OFF_RNN0 = OFF_XW   + (size_t)2*NBEAT*128;      // 200*64
constexpr size_t OFF_RNN1 = OFF_RNN0 + (size_t)NBEAT*64;         // 200*64

// ---------------- fused setup: wa3(8-row GEMM) | init8 | adj-scan ----------------
__global__ __launch_bounds__(192) void k_setup(
    const float* wa, const float* ba, const float* wz, const float* wr, const float* wh,
    const float* note, const float* pv, const float* w_style, const float* b_style,
    const float* w1, const float* b1, const float* w2, const float* b2,
    const float* edges, float* ws, float* dout){
  int blk = blockIdx.x;
  int t = threadIdx.x;
  __shared__ __align__(16) float smem[2392];
  if (blk < NB_WA3){
    float* lrow = smem;            // 299*8
    int base = blk*8;
    for (int x=t; x<8*299; x+=192){
      int r = x & 7, s = x >> 3;
      int R = base + r;
      float v = 0.f;
      if (R < 3588)       v = wa[(size_t)R*FINW + s];
      else if (R == 3588) v = ba[s];
      lrow[s*8 + r] = v;
    }
    __syncthreads();
    if (t < C3){
      const float* Wp; int cc;
      if (t<43){Wp=wz; cc=t;} else if (t<86){Wp=wr; cc=t-43;} else {Wp=wh; cc=t-86;}
      float acc[8];
      #pragma unroll
      for (int r=0;r<8;r++) acc[r]=0.f;
      for (int s=0;s<FINW;s++){
        float w = Wp[s*43+cc];
        float4 lo = *(const float4*)&lrow[s*8];
        float4 hi = *(const float4*)&lrow[s*8+4];
        acc[0]+=lo.x*w; acc[1]+=lo.y*w; acc[2]+=lo.z*w; acc[3]+=lo.w*w;
        acc[4]+=hi.x*w; acc[5]+=hi.y*w; acc[6]+=hi.z*w; acc[7]+=hi.w*w;
      }
      #pragma unroll
      for (int r=0;r<8;r++){
        int R = base + r;
        if (R < 3588){
          if (t<CM) ws[OFF_WA3 + (size_t)R*CM + t] = acc[r];
          else      ws[OFF_WA3X + R]               = acc[r];
        } else if (R == 3588){
          ws[OFF_B3 + t] = acc[r];
        }
      }
    }
  } else if (blk < NB_WA3 + NB_INIT8){
    float* ln    = smem;           // 1024
    float* lh1   = smem + 1024;    // 512
    float* lo    = smem + 1536;    // 88
    float* lperf = smem + 1624;    // 64
    int i0 = (blk - NB_WA3)*8;
    for (int x=t; x<8*128; x+=192){
      int r = x >> 7, k = x & 127;
      ln[k*8 + r] = note[(size_t)(i0+r)*128 + k];
    }
    if (t>=64 && t<128){
      int u=t-64;
      float acc=b_style[u];
      for (int k=0;k<16;k++) acc += pv[k]*w_style[k*64+u];
      lperf[u]=fmaxf(acc,0.f);
    }
    __syncthreads();
    if (t<64){
      float acc[8];
      #pragma unroll
      for (int r=0;r<8;r++) acc[r]=b1[t];
      for (int k=0;k<128;k++){
        float w = w1[k*64+t];
        float4 a = *(const float4*)&ln[k*8];
        float4 b = *(const float4*)&ln[k*8+4];
        acc[0]+=a.x*w; acc[1]+=a.y*w; acc[2]+=a.z*w; acc[3]+=a.w*w;
        acc[4]+=b.x*w; acc[5]+=b.y*w; acc[6]+=b.z*w; acc[7]+=b.w*w;
      }
      #pragma unroll
      for (int r=0;r<8;r++) lh1[t*8+r]=fmaxf(acc[r],0.f);
    }
    __syncthreads();
    if (t<88){
      int r = t & 7, c = t >> 3;
      float acc=b2[c];
      for (int k=0;k<64;k++) acc += lh1[k*8+r]*w2[k*11+c];
      lo[r*11+c]=acc;
      dout[17600 + (size_t)(i0+r)*11 + c] = acc;
    }
    __syncthreads();
    #pragma unroll
    for (int r=0;r<8;r++){
      for (int c=t;c<FINW;c+=192){
        float v;
        if (c<128)      v=ln[c*8+r];
        else if (c<192) v=lperf[c-128];
        else if (c<256) v=0.f;
        else if (c<267) v=lo[r*11+(c-256)];
        else            v=0.f;
        ws[OFF_H + (size_t)(i0+r)*HSTR + c]=v;
      }
    }
  } else {
    int* cur  = (int*)(ws + OFF_CUR);
    int* adjr = (int*)(ws + OFF_ADJR);
    const uint4* p = (const uint4*)edges;
    const unsigned int nvec = 7680000u;
    const unsigned int stride = (unsigned int)NB_SCAN*192u;
    unsigned int v0 = (unsigned int)(blk - NB_WA3 - NB_INIT8)*192u + t;
    for (unsigned int b0 = v0; b0 < nvec; b0 += 4u*stride){
      unsigned int v1=b0+stride, v2=b0+2u*stride, v3=b0+3u*stride;
      bool g1=v1<nvec, g2=v2<nvec, g3=v3<nvec;
      uint4 w0 = p[b0];
      uint4 w1v = g1 ? p[v1] : make_uint4(0,0,0,0);
      uint4 w2v = g2 ? p[v2] : make_uint4(0,0,0,0);
      uint4 w3v = g3 ? p[v3] : make_uint4(0,0,0,0);
      uint4 wv[4] = {w0,w1v,w2v,w3v};
      unsigned int vv[4] = {b0,v1,v2,v3};
      #pragma unroll
      for (int u=0; u<4; u++){
        uint4 w = wv[u];
        if ((w.x|w.y|w.z|w.w)==0u) continue;
        unsigned int base = vv[u]*4u;
        unsigned int arr[4]={w.x,w.y,w.z,w.w};
        #pragma unroll
        for (int q=0;q<4;q++){
          if (arr[q]){
            unsigned int idx=base+q;
            unsigned int j=idx%1600u;
            int slot=atomicAdd(&cur[j],1);
            if (slot<DEG_CAP) adjr[j*DEG_CAP + slot]=(int)(idx/1600u);
          }
        }
      }
    }
  }
}

// ---------------- static message part + M3(h0) (once per seq-iter) ----------------
// dmain: 192 at it=0 (h cols 192..255 exactly zero), 256 at it=1.
__global__ void k_mstat(float* ws, int dmain){
  int e = blockIdx.y; int i0 = blockIdx.x*8;
  int t = threadIdx.x;
  __shared__ float lh[8][256];
  __shared__ float lh2[8][44];
  const float* h = ws + OFF_H;
  for (int x=t; x<512; x+=64){
    int r = x>>6, dq = x&63;
    ((float4*)&lh[r][0])[dq] = ((const float4*)(h + (size_t)(i0+r)*HSTR))[dq];
  }
  for (int x=t; x<88; x+=64){
    int r = x/11, dq = x-r*11;
    ((float4*)&lh2[r][0])[dq] = ((const float4*)(h + (size_t)(i0+r)*HSTR + 256))[dq];
  }
  __syncthreads();
  const float* wm = ws + OFF_WA3 + (size_t)e*FINW*CM;
  int c0 = 2*t;
  float acc[8][2];
  #pragma unroll
  for (int r=0;r<8;r++){acc[r][0]=0.f;acc[r][1]=0.f;}
  for (int d=0; d<dmain; d+=4){
    float4 hv[8];
    #pragma unroll
    for (int r=0;r<8;r++) hv[r] = *(const float4*)&lh[r][d];
    #pragma unroll
    for (int dd=0;dd<4;dd++){
      float2 w = *(const float2*)(wm + (size_t)(d+dd)*CM + c0);
      #pragma unroll
      for (int r=0;r<8;r++){
        float hvv = ((const float*)&hv[r])[dd];
        acc[r][0] += hvv*w.x; acc[r][1] += hvv*w.y;
      }
    }
  }
  float* mst = ws + OFF_MST + ((size_t)e*NN + i0)*CM;
  #pragma unroll
  for (int r=0;r<8;r++) *(float2*)(mst + (size_t)r*CM + c0) = make_float2(acc[r][0],acc[r][1]);
  const float* wd = wm + (size_t)256*CM;
  for (int d=0; d<SECW; d++){
    float2 w = *(const float2*)(wd + (size_t)d*CM + c0);
    #pragma unroll
    for (int r=0;r<8;r++){
      float hvv = lh2[r][d];
      acc[r][0] += hvv*w.x; acc[r][1] += hvv*w.y;
    }
  }
  float* m3 = ws + OFF_M3 + ((size_t)e*NN + i0)*CM;
  #pragma unroll
  for (int r=0;r<8;r++) *(float2*)(m3 + (size_t)r*CM + c0) = make_float2(acc[r][0],acc[r][1]);
  if (t<8){
    const float* wx = ws + OFF_WA3X + (size_t)e*FINW;
    float a=0.f;
    for (int d=0; d<dmain; d++) a += lh[t][d]*wx[d];
    ws[OFF_MSTX + (size_t)e*NN + i0 + t] = a;
    for (int d=0; d<SECW; d++) a += lh2[t][d]*wx[256+d];
    ws[OFF_M3X + (size_t)e*NN + i0 + t] = a;
  }
}

// ---------------- M3 recompute (g>=1) ----------------
__global__ void k_m3dyn(float* ws){
  int e=blockIdx.y, i0=blockIdx.x*8, t=threadIdx.x;
  __shared__ float lhs[8][44];
  const float* h = ws + OFF_H;
  for (int x=t; x<8*43; x+=64){ int r=x/43, d=x-r*43; lhs[r][d]=h[(size_t)(i0+r)*HSTR+256+d]; }
  __syncthreads();
  const float* wd  = ws + OFF_WA3 + ((size_t)e*FINW+256)*CM;
  const float* mst = ws + OFF_MST + ((size_t)e*NN+i0)*CM;
  int c0=2*t;
  float acc[8][2];
  #pragma unroll
  for (int r=0;r<8;r++){ float2 m=*(const float2*)(mst+(size_t)r*CM+c0); acc[r][0]=m.x; acc[r][1]=m.y; }
  for (int d=0; d<43; d++){
    float2 w=*(const float2*)(wd + (size_t)d*CM + c0);
    #pragma unroll
    for (int r=0;r<8;r++){ float hv=lhs[r][d]; acc[r][0]+=hv*w.x; acc[r][1]+=hv*w.y; }
  }
  float* m3 = ws + OFF_M3 + ((size_t)e*NN+i0)*CM;
  #pragma unroll
  for (int r=0;r<8;r++) *(float2*)(m3+(size_t)r*CM+c0)=make_float2(acc[r][0],acc[r][1]);
  if (t<8){
    float a = ws[OFF_MSTX + (size_t)e*NN+i0+t];
    const float* wx = ws + OFF_WA3X + (size_t)e*FINW + 256;
    for (int d=0;d<43;d++) a += lhs[t][d]*wx[d];
    ws[OFF_M3X + (size_t)e*NN+i0+t]=a;
  }
}

// gather (LDS-staged adjacency + 8 independent accumulators) + GRU update
__global__ void k_agg_gru(float* ws, const float* uz, const float* ur, const float* uh){
  int j=blockIdx.x, t=threadIdx.x;   // 128 threads
  __shared__ float lpre[C3];
  __shared__ float lhs[SECW];
  __shared__ float lrh[SECW];
  __shared__ int   ladj[DEG_CAP];
  float* h = ws + OFF_H;
  const int* cur =(const int*)(ws+OFF_CUR);
  const int* adjr=(const int*)(ws+OFF_ADJR) + (size_t)j*DEG_CAP;
  int cnt = cur[j]; if (cnt>DEG_CAP) cnt=DEG_CAP;
  for (int k=t;k<cnt;k+=128) ladj[k]=adjr[k];
  if (t<SECW) lhs[t] = h[(size_t)j*HSTR + 256 + t];
  __syncthreads();
  const float* M3=ws+OFF_M3; const float* M3X=ws+OFF_M3X;
  float a0 = ws[OFF_B3 + t];
  float ax = (t==0)? ws[OFF_B3+128] : 0.f;
  float p1=0.f,p2=0.f,p3=0.f,p4=0.f,p5=0.f,p6=0.f,p7=0.f;
  int k=0;
  for (; k+8<=cnt; k+=8){
    int r0=ladj[k],r1=ladj[k+1],r2=ladj[k+2],r3=ladj[k+3];
    int r4=ladj[k+4],r5=ladj[k+5],r6=ladj[k+6],r7=ladj[k+7];
    a0 += M3[(size_t)r0*CM+t];
    p1 += M3[(size_t)r1*CM+t];
    p2 += M3[(size_t)r2*CM+t];
    p3 += M3[(size_t)r3*CM+t];
    p4 += M3[(size_t)r4*CM+t];
    p5 += M3[(size_t)r5*CM+t];
    p6 += M3[(size_t)r6*CM+t];
    p7 += M3[(size_t)r7*CM+t];
    if (t==0) ax += ((M3X[r0]+M3X[r1])+(M3X[r2]+M3X[r3]))
                  + ((M3X[r4]+M3X[r5])+(M3X[r6]+M3X[r7]));
  }
  for (; k<cnt; k++){ int r=ladj[k]; a0+=M3[(size_t)r*CM+t]; if(t==0) ax+=M3X[r]; }
  a0 += ((p1+p2)+(p3+p4)) + ((p5+p6)+p7);
  lpre[t]=a0; if (t==0) lpre[128]=ax;
  __syncthreads();
  float z=0.f;
  if (t<SECW){
    float az=lpre[t], ar=lpre[43+t];
    for (int d=0;d<SECW;d++){ float hv=lhs[d]; az+=hv*uz[d*43+t]; ar+=hv*ur[d*43+t]; }
    z=sigm(az);
    float r=sigm(ar);
    lrh[t]=r*lhs[t];
  }
  __syncthreads();
  if (t<SECW){
    float ah=lpre[86+t];
    for (int d=0;d<SECW;d++) ah += lrh[d]*uh[d*43+t];
    float cand=tanh_(ah);
    h[(size_t)j*HSTR+256+t] = (1.f-z)*lhs[t] + z*cand;
  }
}

// ---------------- beat attention + layer-0 LSTM input projection (fused) ----------------
// xw written TRANSPOSED ([dir*128+col]*NBEAT + beat) and PRE-SCALED.
__global__ void k_attn_xw(float* ws, const float* mw, const float* mb, const float* mc,
                          const float* bw, const float* bb, const float* bc,
                          const float* res,
                          const float* w0f, const float* bia0f,
                          const float* w0b, const float* bia0b, float* xw){
  int b=blockIdx.x, t=threadIdx.x;  // 128 threads
  float* h=ws+OFF_H;
  __shared__ float sm[8][8];
  __shared__ float wgt[8][8];
  __shared__ float sb[8];
  __shared__ float wb_[8];
  __shared__ float lb[52];
  int n=t>>3, hh=t&7;
  if (t<64){
    const float* mrow = h + (size_t)(b*8+n)*HSTR + 267;
    float sim=0.f;
    for (int d=0;d<4;d++){
      int c=hh*4+d;
      float acc=mb[c];
      for (int k=0;k<32;k++) acc += mrow[k]*mw[k*32+c];
      sim += tanh_(acc)*mc[c];
    }
    sm[n][hh]=sim;
  }
  if (t<8){
    const float* irow = h + (size_t)(b*8+t)*HSTR + 256;
    float sim=0.f;
    for (int d=0;d<11;d++){
      float acc=bb[d];
      for (int k=0;k<11;k++) acc += irow[k]*bw[k*11+d];
      sim += tanh_(acc)*bc[d];
    }
    sb[t]=sim;
  }
  __syncthreads();
  if (t<64){
    float m=-1e30f;
    for (int q=0;q<8;q++) m=fmaxf(m, sm[q][hh]);
    float Z=0.f;
    for (int q=0;q<8;q++) Z+=__expf(sm[q][hh]-m);
    wgt[n][hh]=__expf(sm[n][hh]-m)/Z;
  }
  if (t<8){
    float m=-1e30f;
    for (int q=0;q<8;q++) m=fmaxf(m, sb[q]);
    float Z=0.f;
    for (int q=0;q<8;q++) Z+=__expf(sb[q]-m);
    wb_[t]=__expf(sb[t]-m)/Z;
  }
  __syncthreads();
  if (t<32){
    int hh2=t>>2;
    float acc=0.f;
    for (int q=0;q<8;q++) acc += wgt[q][hh2]* h[(size_t)(b*8+q)*HSTR + 267 + t];
    lb[11+t]=acc;
  }
  if (t<11){
    float acc=0.f;
    for (int q=0;q<8;q++) acc += wb_[q]* h[(size_t)(b*8+q)*HSTR + 256 + t];
    lb[t]=acc;
  }
  if (t<8) lb[43+t]=res[b*8+t];
  __syncthreads();
  float acc0=bia0f[t], acc1=bia0b[t];
  for (int k=0;k<51;k++){
    float v=lb[k];
    acc0 += v*w0f[t*51+k];
    acc1 += v*w0b[t*51+k];
  }
  float sc = gate_scale(t);
  xw[((size_t)t)*NBEAT + b]       = acc0*sc;
  xw[((size_t)(128+t))*NBEAT + b] = acc1*sc;
}

// ---------------- LSTM scan core (lane-parameterized for fused k_beat) ----------------
template<int DIR>
__device__ __forceinline__ void chunk8(int c, const float4& A0, const float4& A1,
    const float4& B0, const float4& B1,
    float* hu, float& creg, const float4* rA, const float4* rB,
    float cb1, float cb0, int l, float* out){
  float cxA[8] = {A0.x,A0.y,A0.z,A0.w,A1.x,A1.y,A1.z,A1.w};
  float cxB[8] = {B0.x,B0.y,B0.z,B0.w,B1.x,B1.y,B1.z,B1.w};
  float hst[8];
  #pragma unroll
  for (int u=0; u<8; u++){
    const int e = DIR ? (7-u) : u;
    float av[8], bv[8];
    #pragma unroll
    for (int q=0; q<8; q++){
      av[q] = hu[4*q+0]*rA[q].x + hu[4*q+1]*rA[q].y + hu[4*q+2]*rA[q].z + hu[4*q+3]*rA[q].w;
      bv[q] = hu[4*q+0]*rB[q].x + hu[4*q+1]*rB[q].y + hu[4*q+2]*rB[q].z + hu[4*q+3]*rB[q].w;
    }
    float accA = cxA[e] + (((av[0]+av[1])+(av[2]+av[3])) + ((av[4]+av[5])+(av[6]+av[7])));
    float accB = cxB[e] + (((bv[0]+bv[1])+(bv[2]+bv[3])) + ((bv[4]+bv[5])+(bv[6]+bv[7])));
    float pA  = frcp(1.f + fexp2(accA));            // sigm(i) low | sigm(f) high
    float rBv = frcp(1.f + fexp2(accB));
    float pB  = __builtin_fmaf(rBv, cb1, cb0);      // K2C*tanh(g) low | sigm(o) high
    float prod = pA * pB;                           // K2C*(i*g) in low lanes
    float prodIn = swap_lo_to_hi(prod);             // high lane l <- prod[l-32] (VALU)
    creg = __builtin_fmaf(pA, creg, prodIn);        // scaled c update (valid high lanes)
    float T = __builtin_fmaf(frcp(1.f + fexp2(creg)), 2.f, -1.f);  // tanh(c)
    float hnew = pB * T;                            // sigm(o)*tanh(c) (valid high lanes)
    hst[u] = hnew;
    #pragma unroll
    for (int d=0; d<32; d++)                        // broadcast h -> SGPRs for next step
      hu[d] = __uint_as_float(__builtin_amdgcn_readlane(__float_as_uint(hnew), 32+d));
  }
  if (l >= 32){
    int j = l - 32;
    #pragma unroll
    for (int u=0; u<8; u++){
      int s = c*8 + u;
      int tt = DIR ? (199 - s) : s;
      out[(size_t)tt*64 + DIR*32 + j] = hst[u];
    }
  }
}

template<int DIR>
__device__ __forceinline__ void lstm_scan(int l, const float* xwT, const float* whh, float* out){
  const float sB = (l < 32) ? K2C : K1C;
  float4 rA[8], rB[8];
  #pragma unroll
  for (int q=0; q<8; q++){
    float4 a = *(const float4*)&whh[l*32 + q*4];
    float4 b = *(const float4*)&whh[(l+64)*32 + q*4];
    rA[q] = make_float4(a.x*K1C, a.y*K1C, a.z*K1C, a.w*K1C);
    rB[q] = make_float4(b.x*sB,  b.y*sB,  b.z*sB,  b.w*sB);
  }
  const float cb1 = (l < 32) ? (2.f*K2C) : 1.f;
  const float cb0 = (l < 32) ? (-K2C)    : 0.f;
  const float* xA = xwT + ((size_t)DIR*128 + l)*NBEAT;
  const float* xB = xwT + ((size_t)DIR*128 + 64 + l)*NBEAT;
  float hu[32];
  #pragma unroll
  for (int d=0; d<32; d++) hu[d] = 0.f;
  float creg = 0.f;
  float4 A0,A1,B0,B1, P0,P1,Q0,Q1;
#define LOADC(cidx, a0,a1,b0,b1) do {               \
    int _b = DIR ? (192 - (cidx)*8) : ((cidx)*8);   \
    a0 = *(const float4*)&xA[_b];                   \
    a1 = *(const float4*)&xA[_b+4];                 \
    b0 = *(const float4*)&xB[_b];                   \
    b1 = *(const float4*)&xB[_b+4];                 \
  } while(0)
  LOADC(0, A0,A1,B0,B1);
  for (int cc=0; cc<12; cc++){
    int c0 = 2*cc;
    LOADC(c0+1, P0,P1,Q0,Q1);
    chunk8<DIR>(c0,   A0,A1,B0,B1, hu, creg, rA, rB, cb1, cb0, l, out);
    LOADC(c0+2, A0,A1,B0,B1);
    chunk8<DIR>(c0+1, P0,P1,Q0,Q1, hu, creg, rA, rB, cb1, cb0, l, out);
  }
  chunk8<DIR>(24, A0,A1,B0,B1, hu, creg, rA, rB, cb1, cb0, l, out);
#undef LOADC
}

// ---------------- fused beat chain: scan0 | xw1 | scan1 in ONE dispatch ----------------
// Single block, 512 threads. Waves 0/1 run the two directions of each scan (the
// recurrences are independent); ALL 512 threads compute the layer-1 input
// projection between them. Same-CU global RAW across __syncthreads is safe
// (compiler drains vmcnt before s_barrier; L1 is same-CU). Removes 2 dispatches
// + 2 ~10us gaps per seq-iter (R7 showed grid-wide barriers cost ~160us -- this
// fusion needs none).
__global__ __launch_bounds__(512,1) void k_beat(float* ws,
    const float* whh0f, const float* whh0b,
    const float* wih1f, const float* b1f, const float* wih1b, const float* b1b,
    const float* whh1f, const float* whh1b){
  const int tid = threadIdx.x;
  float* xw0  = ws + OFF_XW;
  float* rnn0 = ws + OFF_RNN0;
  float* rnn1 = ws + OFF_RNN1;
  // phase A: layer-0 scan (waves 0,1)
  if (tid < 64)        lstm_scan<0>(tid,      xw0, whh0f, rnn0);
  else if (tid < 128)  lstm_scan<1>(tid & 63, xw0, whh0b, rnn0);
  __syncthreads();
  // phase B: xw1 = rnn0 @ wih1 (transposed, pre-scaled) -- all 512 threads
  {
    int sub = tid >> 7;      // 0..3: which (tt,dir) unit group
    int c   = tid & 127;     // output col
    float scl = gate_scale(c);
    for (int u = sub; u < 2*NBEAT; u += 4){
      int tt = u >> 1, dir = u & 1;
      const float* w   = dir ? wih1b : wih1f;
      const float* bia = dir ? b1b   : b1f;
      const float* row = rnn0 + (size_t)tt*64;
      float acc = bia[c];
      #pragma unroll 8
      for (int k=0; k<64; k++) acc += row[k]*w[c*64+k];
      xw0[((size_t)(dir*128 + c))*NBEAT + tt] = acc*scl;   // overwrite xw buffer
    }
  }
  __syncthreads();
  // phase C: layer-1 scan (waves 0,1)
  if (tid < 64)        lstm_scan<0>(tid,      xw0, whh1f, rnn1);
  else if (tid < 128)  lstm_scan<1>(tid & 63, xw0, whh1b, rnn1);
}

// ---------------- fc head + final_out + h update (tempo fused) ----------------
__global__ void k_fc(float* ws, const int* bn, const float* w1, const float* b1,
                     const float* w2, const float* b2,
                     const float* wt, const float* bt, float* dout, int it){
  int i=blockIdx.x, t=threadIdx.x;   // 64 threads
  __shared__ float row[FINW];
  __shared__ float hid[32];
  __shared__ float fo[11];
  float* h=ws+OFF_H;
  int b = bn[i];
  const float* rnn = ws+OFF_RNN1;
  for (int c=t;c<FINW;c+=64){
    float v;
    if (c>=192 && c<256){ v=rnn[(size_t)b*64 + c-192]; h[(size_t)i*HSTR+c]=v; }
    else v=h[(size_t)i*HSTR+c];
    row[c]=v;
  }
  float tv = rnn[(size_t)b*64 + t]*wt[t];
  #pragma unroll
  for (int off=32; off; off>>=1) tv += __shfl_xor(tv, off, 64);
  __syncthreads();
  if (t<32){
    float acc=b1[t];
    for (int k=0;k<FINW;k++) acc += row[k]*w1[k*32+t];
    hid[t]=fmaxf(acc,0.f);
  }
  __syncthreads();
  if (t<10){
    float acc=b2[t];
    for (int m=0;m<32;m++) acc += hid[m]*w2[m*10+t];
    fo[1+t]=acc;
  }
  if (t==0) fo[0]=tv + bt[0];
  __syncthreads();
  if (t<11){
    float v=fo[t];
    h[(size_t)i*HSTR+256+t]=v;
    dout[(size_t)(2+it)*17600 + i*11 + t]=v;
    if (it==1) dout[i*11+t]=v;
  }
}

// ---------------- launcher ----------------
extern "C" void kernel_launch(void* const* d_in, const int* in_sizes, int n_in,
                              void* d_out, int out_size, void* d_ws, size_t ws_size,
                              hipStream_t stream){
  (void)in_sizes; (void)n_in; (void)out_size; (void)ws_size;
  float* ws=(float*)d_ws;
  const float* note    =(const float*)d_in[0];
  const float* pv      =(const float*)d_in[1];
  const float* res     =(const float*)d_in[2];
  const float* edges   =(const float*)d_in[3];
  const int*   bn      =(const int*)d_in[4];
  const float* w_style =(const float*)d_in[5];
  const float* b_style =(const float*)d_in[6];
  const float* w_init1 =(const float*)d_in[7];
  const float* b_init1 =(const float*)d_in[8];
  const float* w_init2 =(const float*)d_in[9];
  const float* b_init2 =(const float*)d_in[10];
  const float* gg_wa   =(const float*)d_in[11];
  const float* gg_ba   =(const float*)d_in[12];
  const float* gg_wz   =(const float*)d_in[13];
  const float* gg_wr   =(const float*)d_in[14];
  const float* gg_wh   =(const float*)d_in[15];
  const float* gg_uz   =(const float*)d_in[16];
  const float* gg_ur   =(const float*)d_in[17];
  const float* gg_uh   =(const float*)d_in[18];
  const float* abw     =(const float*)d_in[19];
  const float* abb     =(const float*)d_in[20];
  const float* abc     =(const float*)d_in[21];
  const float* amw     =(const float*)d_in[22];
  const float* amb     =(const float*)d_in[23];
  const float* amc     =(const float*)d_in[24];
  const float* wih0f   =(const float*)d_in[25];
  const float* whh0f   =(const float*)d_in[26];
  const float* b0f     =(const float*)d_in[27];
  const float* wih0b   =(const float*)d_in[28];
  const float* whh0b   =(const float*)d_in[29];
  const float* b0b     =(const float*)d_in[30];
  const float* wih1f   =(const float*)d_in[31];
  const float* whh1f   =(const float*)d_in[32];
  const float* b1f     =(const float*)d_in[33];
  const float* wih1b   =(const float*)d_in[34];
  const float* whh1b   =(const float*)d_in[35];
  const float* b1b     =(const float*)d_in[36];
  const float* w_tempo =(const float*)d_in[37];
  const float* b_tempo =(const float*)d_in[38];
  const float* w_fc1   =(const float*)d_in[39];
  const float* b_fc1   =(const float*)d_in[40];
  const float* w_fc2   =(const float*)d_in[41];
  const float* b_fc2   =(const float*)d_in[42];
  float* dout=(float*)d_out;

  hipMemsetAsync(ws+OFF_CUR, 0, NN*sizeof(int), stream);
  k_setup<<<NB_WA3+NB_INIT8+NB_SCAN,192,0,stream>>>(
      gg_wa,gg_ba,gg_wz,gg_wr,gg_wh,
      note,pv,w_style,b_style,w_init1,b_init1,w_init2,b_init2,
      edges,ws,dout);

  for (int it=0; it<2; it++){
    k_mstat<<<dim3(200,12),64,0,stream>>>(ws, it==0 ? 192 : 256);   // also emits M3(h0)
    k_agg_gru<<<NN,128,0,stream>>>(ws,gg_uz,gg_ur,gg_uh);           // g=0
    for (int g=1; g<3; g++){
      k_m3dyn<<<dim3(200,12),64,0,stream>>>(ws);
      k_agg_gru<<<NN,128,0,stream>>>(ws,gg_uz,gg_ur,gg_uh);
    }
    k_attn_xw<<<NBEAT,128,0,stream>>>(ws,amw,amb,amc,abw,abb,abc,res,
                                      wih0f,b0f,wih0b,b0b,ws+OFF_XW);
    k_beat<<<1,512,0,stream>>>(ws,whh0f,whh0b,wih1f,b1f,wih1b,b1b,whh1f,whh1b);
    k_fc<<<NN,64,0,stream>>>(ws,bn,w_fc1,b_fc1,w_fc2,b_fc2,w_tempo,b_tempo,dout,it);
  }
}

// Round 9
// 740.881 us; speedup vs baseline: 2.8569x; 2.3383x over previous
//
#include <hip/hip_runtime.h>
#include <stdint.h>

// ---------------- problem constants ----------------
#define NN     1600
#define NBEAT  200
#define FINW   299
#define HSTR   300      // padded row stride for h
#define SECW   43
#define EDG    12
#define C3     129      // 3*43 projected width
#define CM     128      // main columns (129th handled separately)
#define DEG_CAP 256     // per-destination adjacency bucket (mean 77, max~112)

// fused-setup block ranges (all 192-thread blocks). ROLES FIRST (R2 config --
// best measured). R3's exact-residency grid did NOT speed the scan; R6/R7 grid
// barriers cost ~160us each at 1024 blocks; R8 single-CU beat fusion thrashes
// L1 (64KB whh working set vs 32KB L1). This launch structure is the proven one.
#define NB_WA3   450
#define NB_INIT8 200
#define NB_SCAN  2560

// exp2/rcp-based fast activations: -log2e and -2*log2e scales folded in.
#define K1C (-1.4426950408889634f)
#define K2C (-2.8853900817779268f)

#if __has_builtin(__builtin_amdgcn_exp2f)
__device__ __forceinline__ float fexp2(float x){ return __builtin_amdgcn_exp2f(x); }
#else
__device__ __forceinline__ float fexp2(float x){ return exp2f(x); }
#endif
#if __has_builtin(__builtin_amdgcn_rcpf)
__device__ __forceinline__ float frcp(float x){ return __builtin_amdgcn_rcpf(x); }
#else
__device__ __forceinline__ float frcp(float x){ return 1.0f/x; }
#endif

__device__ __forceinline__ float sigm(float x){ return frcp(1.f + fexp2(K1C*x)); }
__device__ __forceinline__ float tanh_(float x){ return __builtin_fmaf(frcp(1.f + fexp2(K2C*x)), 2.f, -1.f); }

// gate column -> activation input scale (i,f,o sigmoid: K1C; g tanh: K2C)
__device__ __forceinline__ float gate_scale(int col){
  return (col >= 64 && col < 96) ? K2C : K1C;
}

// high lane l receives v from lane l-32 (VALU permlane, no lgkm wait on the
// serial LSTM chain). r[0] high lane l = v[l-32]  (verified R5; R4 bug was r[1]).
__device__ __forceinline__ float swap_lo_to_hi(float v){
#if __has_builtin(__builtin_amdgcn_permlane32_swap)
  typedef unsigned u32x2 __attribute__((ext_vector_type(2)));
  u32x2 r = __builtin_amdgcn_permlane32_swap(__float_as_uint(v), __float_as_uint(v), false, false);
  return __uint_as_float(r[0]);
#else
  return __shfl(v, (int)(threadIdx.x & 31), 64);
#endif
}

// ---------------- workspace layout (4-byte words) ----------------
constexpr size_t OFF_H    = 0;                                   // 1600*300
constexpr size_t OFF_WA3  = OFF_H    + (size_t)NN*HSTR;          // 12*299*128
constexpr size_t OFF_WA3X = OFF_WA3  + (size_t)EDG*FINW*CM;      // 12*299
constexpr size_t OFF_B3   = OFF_WA3X + (size_t)EDG*FINW;         // 132
constexpr size_t OFF_MST  = OFF_B3   + 132;                      // 12*1600*128
constexpr size_t OFF_MSTX = OFF_MST  + (size_t)EDG*NN*CM;        // 12*1600
constexpr size_t OFF_M3   = OFF_MSTX + (size_t)EDG*NN;           // 12*1600*128
constexpr size_t OFF_M3X  = OFF_M3   + (size_t)EDG*NN*CM;        // 12*1600
constexpr size_t OFF_CUR  = OFF_M3X  + (size_t)EDG*NN;           // 1600 ints
constexpr size_t OFF_ADJR = OFF_CUR  + NN;                       // 1600*256 ints
constexpr size_t OFF_XW   = OFF_ADJR + (size_t)NN*DEG_CAP;       // 2*128*200 (TRANSPOSED: [dir*128+col][beat])
constexpr size_t OFF_RNN0 = OFF_XW   + (size_t)2*NBEAT*128;      // 200*64
constexpr size_t OFF_RNN1 = OFF_RNN0 + (size_t)NBEAT*64;         // 200*64

// ---------------- fused setup: wa3(8-row GEMM) | init8 | adj-scan (one dispatch) ----------------
// Single manually-unioned LDS buffer: 2392 floats = 9568 B keeps 10 blocks/CU.
__global__ __launch_bounds__(192) void k_setup(
    const float* wa, const float* ba, const float* wz, const float* wr, const float* wh,
    const float* note, const float* pv, const float* w_style, const float* b_style,
    const float* w1, const float* b1, const float* w2, const float* b2,
    const float* edges, float* ws, float* dout){
  int blk = blockIdx.x;
  int t = threadIdx.x;
  __shared__ __align__(16) float smem[2392];
  if (blk < NB_WA3){
    // ---- wa3 as blocked GEMM: 8 rows of [3588x299]@[299x129] per block.
    float* lrow = smem;            // 299*8 = 2392 floats
    int base = blk*8;              // row base in [0,3600); row 3588 = ba; 3589+ skipped
    for (int x=t; x<8*299; x+=192){
      int r = x & 7, s = x >> 3;
      int R = base + r;
      float v = 0.f;
      if (R < 3588)       v = wa[(size_t)R*FINW + s];
      else if (R == 3588) v = ba[s];
      lrow[s*8 + r] = v;
    }
    __syncthreads();
    if (t < C3){
      const float* Wp; int cc;
      if (t<43){Wp=wz; cc=t;} else if (t<86){Wp=wr; cc=t-43;} else {Wp=wh; cc=t-86;}
      float acc[8];
      #pragma unroll
      for (int r=0;r<8;r++) acc[r]=0.f;
      for (int s=0;s<FINW;s++){
        float w = Wp[s*43+cc];
        float4 lo = *(const float4*)&lrow[s*8];
        float4 hi = *(const float4*)&lrow[s*8+4];
        acc[0]+=lo.x*w; acc[1]+=lo.y*w; acc[2]+=lo.z*w; acc[3]+=lo.w*w;
        acc[4]+=hi.x*w; acc[5]+=hi.y*w; acc[6]+=hi.z*w; acc[7]+=hi.w*w;
      }
      #pragma unroll
      for (int r=0;r<8;r++){
        int R = base + r;
        if (R < 3588){
          if (t<CM) ws[OFF_WA3 + (size_t)R*CM + t] = acc[r];
          else      ws[OFF_WA3X + R]               = acc[r];
        } else if (R == 3588){
          ws[OFF_B3 + t] = acc[r];
        }
      }
    }
  } else if (blk < NB_WA3 + NB_INIT8){
    // ---- init8: 8 notes per block, wa3-style weight amortization.
    float* ln    = smem;           // 128*8 = 1024
    float* lh1   = smem + 1024;    // 64*8  = 512
    float* lo    = smem + 1536;    // 8*11  = 88
    float* lperf = smem + 1624;    // 64
    int i0 = (blk - NB_WA3)*8;
    for (int x=t; x<8*128; x+=192){
      int r = x >> 7, k = x & 127;
      ln[k*8 + r] = note[(size_t)(i0+r)*128 + k];
    }
    if (t>=64 && t<128){
      int u=t-64;
      float acc=b_style[u];
      for (int k=0;k<16;k++) acc += pv[k]*w_style[k*64+u];
      lperf[u]=fmaxf(acc,0.f);
    }
    __syncthreads();
    if (t<64){
      float acc[8];
      #pragma unroll
      for (int r=0;r<8;r++) acc[r]=b1[t];
      for (int k=0;k<128;k++){
        float w = w1[k*64+t];
        float4 a = *(const float4*)&ln[k*8];
        float4 b = *(const float4*)&ln[k*8+4];
        acc[0]+=a.x*w; acc[1]+=a.y*w; acc[2]+=a.z*w; acc[3]+=a.w*w;
        acc[4]+=b.x*w; acc[5]+=b.y*w; acc[6]+=b.z*w; acc[7]+=b.w*w;
      }
      #pragma unroll
      for (int r=0;r<8;r++) lh1[t*8+r]=fmaxf(acc[r],0.f);
    }
    __syncthreads();
    if (t<88){
      int r = t & 7, c = t >> 3;   // c in [0,11)
      float acc=b2[c];
      for (int k=0;k<64;k++) acc += lh1[k*8+r]*w2[k*11+c];
      lo[r*11+c]=acc;
      dout[17600 + (size_t)(i0+r)*11 + c] = acc;
    }
    __syncthreads();
    #pragma unroll
    for (int r=0;r<8;r++){
      for (int c=t;c<FINW;c+=192){
        float v;
        if (c<128)      v=ln[c*8+r];
        else if (c<192) v=lperf[c-128];
        else if (c<256) v=0.f;
        else if (c<267) v=lo[r*11+(c-256)];
        else            v=0.f;
        ws[OFF_H + (size_t)(i0+r)*HSTR + c]=v;
      }
    }
  } else {
    // ---- adj: sparse edge extraction into fixed-width buckets.
    int* cur  = (int*)(ws + OFF_CUR);
    int* adjr = (int*)(ws + OFF_ADJR);
    const uint4* p = (const uint4*)edges;
    const unsigned int nvec = 7680000u;   // 12*1600*1600/4
    const unsigned int stride = (unsigned int)NB_SCAN*192u;
    unsigned int v0 = (unsigned int)(blk - NB_WA3 - NB_INIT8)*192u + t;
    for (unsigned int b0 = v0; b0 < nvec; b0 += 4u*stride){
      unsigned int v1=b0+stride, v2=b0+2u*stride, v3=b0+3u*stride;
      bool g1=v1<nvec, g2=v2<nvec, g3=v3<nvec;
      uint4 w0 = p[b0];
      uint4 w1v = g1 ? p[v1] : make_uint4(0,0,0,0);
      uint4 w2v = g2 ? p[v2] : make_uint4(0,0,0,0);
      uint4 w3v = g3 ? p[v3] : make_uint4(0,0,0,0);
      uint4 wv[4] = {w0,w1v,w2v,w3v};
      unsigned int vv[4] = {b0,v1,v2,v3};
      #pragma unroll
      for (int u=0; u<4; u++){
        uint4 w = wv[u];
        if ((w.x|w.y|w.z|w.w)==0u) continue;
        unsigned int base = vv[u]*4u;
        unsigned int arr[4]={w.x,w.y,w.z,w.w};
        #pragma unroll
        for (int q=0;q<4;q++){
          if (arr[q]){
            unsigned int idx=base+q;
            unsigned int j=idx%1600u;
            int slot=atomicAdd(&cur[j],1);
            if (slot<DEG_CAP) adjr[j*DEG_CAP + slot]=(int)(idx/1600u);  // row = e*1600+i
          }
        }
      }
    }
  }
}

// ---------------- static message part + M3(h0) (once per seq-iter) ----------------
// dmain: 192 at it=0 (h cols 192..255 are exactly zero -> skip 25% of wm reads),
// 256 at it=1.
__global__ void k_mstat(float* ws, int dmain){
  int e = blockIdx.y; int i0 = blockIdx.x*8;
  int t = threadIdx.x;
  __shared__ float lh[8][256];
  __shared__ float lh2[8][44];
  const float* h = ws + OFF_H;
  for (int x=t; x<512; x+=64){
    int r = x>>6, dq = x&63;
    ((float4*)&lh[r][0])[dq] = ((const float4*)(h + (size_t)(i0+r)*HSTR))[dq];
  }
  for (int x=t; x<88; x+=64){
    int r = x/11, dq = x-r*11;
    ((float4*)&lh2[r][0])[dq] = ((const float4*)(h + (size_t)(i0+r)*HSTR + 256))[dq];
  }
  __syncthreads();
  const float* wm = ws + OFF_WA3 + (size_t)e*FINW*CM;
  int c0 = 2*t;
  float acc[8][2];
  #pragma unroll
  for (int r=0;r<8;r++){acc[r][0]=0.f;acc[r][1]=0.f;}
  for (int d=0; d<dmain; d+=4){
    float4 hv[8];
    #pragma unroll
    for (int r=0;r<8;r++) hv[r] = *(const float4*)&lh[r][d];
    #pragma unroll
    for (int dd=0;dd<4;dd++){
      float2 w = *(const float2*)(wm + (size_t)(d+dd)*CM + c0);
      #pragma unroll
      for (int r=0;r<8;r++){
        float hvv = ((const float*)&hv[r])[dd];
        acc[r][0] += hvv*w.x; acc[r][1] += hvv*w.y;
      }
    }
  }
  float* mst = ws + OFF_MST + ((size_t)e*NN + i0)*CM;
  #pragma unroll
  for (int r=0;r<8;r++) *(float2*)(mst + (size_t)r*CM + c0) = make_float2(acc[r][0],acc[r][1]);
  // continue over dynamic cols 256..298 -> M3 = mst + hs@wd
  const float* wd = wm + (size_t)256*CM;
  for (int d=0; d<SECW; d++){
    float2 w = *(const float2*)(wd + (size_t)d*CM + c0);
    #pragma unroll
    for (int r=0;r<8;r++){
      float hvv = lh2[r][d];
      acc[r][0] += hvv*w.x; acc[r][1] += hvv*w.y;
    }
  }
  float* m3 = ws + OFF_M3 + ((size_t)e*NN + i0)*CM;
  #pragma unroll
  for (int r=0;r<8;r++) *(float2*)(m3 + (size_t)r*CM + c0) = make_float2(acc[r][0],acc[r][1]);
  if (t<8){
    const float* wx = ws + OFF_WA3X + (size_t)e*FINW;
    float a=0.f;
    for (int d=0; d<dmain; d++) a += lh[t][d]*wx[d];
    ws[OFF_MSTX + (size_t)e*NN + i0 + t] = a;
    for (int d=0; d<SECW; d++) a += lh2[t][d]*wx[256+d];
    ws[OFF_M3X + (size_t)e*NN + i0 + t] = a;
  }
}

// ---------------- M3 recompute (g>=1) ----------------
__global__ void k_m3dyn(float* ws){
  int e=blockIdx.y, i0=blockIdx.x*8, t=threadIdx.x;
  __shared__ float lhs[8][44];
  const float* h = ws + OFF_H;
  for (int x=t; x<8*43; x+=64){ int r=x/43, d=x-r*43; lhs[r][d]=h[(size_t)(i0+r)*HSTR+256+d]; }
  __syncthreads();
  const float* wd  = ws + OFF_WA3 + ((size_t)e*FINW+256)*CM;
  const float* mst = ws + OFF_MST + ((size_t)e*NN+i0)*CM;
  int c0=2*t;
  float acc[8][2];
  #pragma unroll
  for (int r=0;r<8;r++){ float2 m=*(const float2*)(mst+(size_t)r*CM+c0); acc[r][0]=m.x; acc[r][1]=m.y; }
  for (int d=0; d<43; d++){
    float2 w=*(const float2*)(wd + (size_t)d*CM + c0);
    #pragma unroll
    for (int r=0;r<8;r++){ float hv=lhs[r][d]; acc[r][0]+=hv*w.x; acc[r][1]+=hv*w.y; }
  }
  float* m3 = ws + OFF_M3 + ((size_t)e*NN+i0)*CM;
  #pragma unroll
  for (int r=0;r<8;r++) *(float2*)(m3+(size_t)r*CM+c0)=make_float2(acc[r][0],acc[r][1]);
  if (t<8){
    float a = ws[OFF_MSTX + (size_t)e*NN+i0+t];
    const float* wx = ws + OFF_WA3X + (size_t)e*FINW + 256;
    for (int d=0;d<43;d++) a += lhs[t][d]*wx[d];
    ws[OFF_M3X + (size_t)e*NN+i0+t]=a;
  }
}

// gather (LDS-staged adjacency + 8 independent accumulators) + GRU update
__global__ void k_agg_gru(float* ws, const float* uz, const float* ur, const float* uh){
  int j=blockIdx.x, t=threadIdx.x;   // 128 threads
  __shared__ float lpre[C3];
  __shared__ float lhs[SECW];
  __shared__ float lrh[SECW];
  __shared__ int   ladj[DEG_CAP];
  float* h = ws + OFF_H;
  const int* cur =(const int*)(ws+OFF_CUR);
  const int* adjr=(const int*)(ws+OFF_ADJR) + (size_t)j*DEG_CAP;
  int cnt = cur[j]; if (cnt>DEG_CAP) cnt=DEG_CAP;
  for (int k=t;k<cnt;k+=128) ladj[k]=adjr[k];
  if (t<SECW) lhs[t] = h[(size_t)j*HSTR + 256 + t];
  __syncthreads();
  const float* M3=ws+OFF_M3; const float* M3X=ws+OFF_M3X;
  float a0 = ws[OFF_B3 + t];
  float ax = (t==0)? ws[OFF_B3+128] : 0.f;
  float p1=0.f,p2=0.f,p3=0.f,p4=0.f,p5=0.f,p6=0.f,p7=0.f;
  int k=0;
  for (; k+8<=cnt; k+=8){
    int r0=ladj[k],r1=ladj[k+1],r2=ladj[k+2],r3=ladj[k+3];
    int r4=ladj[k+4],r5=ladj[k+5],r6=ladj[k+6],r7=ladj[k+7];
    a0 += M3[(size_t)r0*CM+t];
    p1 += M3[(size_t)r1*CM+t];
    p2 += M3[(size_t)r2*CM+t];
    p3 += M3[(size_t)r3*CM+t];
    p4 += M3[(size_t)r4*CM+t];
    p5 += M3[(size_t)r5*CM+t];
    p6 += M3[(size_t)r6*CM+t];
    p7 += M3[(size_t)r7*CM+t];
    if (t==0) ax += ((M3X[r0]+M3X[r1])+(M3X[r2]+M3X[r3]))
                  + ((M3X[r4]+M3X[r5])+(M3X[r6]+M3X[r7]));
  }
  for (; k<cnt; k++){ int r=ladj[k]; a0+=M3[(size_t)r*CM+t]; if(t==0) ax+=M3X[r]; }
  a0 += ((p1+p2)+(p3+p4)) + ((p5+p6)+p7);
  lpre[t]=a0; if (t==0) lpre[128]=ax;
  __syncthreads();
  float z=0.f;
  if (t<SECW){
    float az=lpre[t], ar=lpre[43+t];
    for (int d=0;d<SECW;d++){ float hv=lhs[d]; az+=hv*uz[d*43+t]; ar+=hv*ur[d*43+t]; }
    z=sigm(az);
    float r=sigm(ar);
    lrh[t]=r*lhs[t];
  }
  __syncthreads();
  if (t<SECW){
    float ah=lpre[86+t];
    for (int d=0;d<SECW;d++) ah += lrh[d]*uh[d*43+t];
    float cand=tanh_(ah);
    h[(size_t)j*HSTR+256+t] = (1.f-z)*lhs[t] + z*cand;
  }
}

// ---------------- beat attention + layer-0 LSTM input projection (fused) ----------------
// xw written TRANSPOSED ([dir*128+col]*NBEAT + beat) and PRE-SCALED.
__global__ void k_attn_xw(float* ws, const float* mw, const float* mb, const float* mc,
                          const float* bw, const float* bb, const float* bc,
                          const float* res,
                          const float* w0f, const float* bia0f,
                          const float* w0b, const float* bia0b, float* xw){
  int b=blockIdx.x, t=threadIdx.x;  // 128 threads
  float* h=ws+OFF_H;
  __shared__ float sm[8][8];
  __shared__ float wgt[8][8];
  __shared__ float sb[8];
  __shared__ float wb_[8];
  __shared__ float lb[52];
  int n=t>>3, hh=t&7;
  if (t<64){
    const float* mrow = h + (size_t)(b*8+n)*HSTR + 267;
    float sim=0.f;
    for (int d=0;d<4;d++){
      int c=hh*4+d;
      float acc=mb[c];
      for (int k=0;k<32;k++) acc += mrow[k]*mw[k*32+c];
      sim += tanh_(acc)*mc[c];
    }
    sm[n][hh]=sim;
  }
  if (t<8){
    const float* irow = h + (size_t)(b*8+t)*HSTR + 256;
    float sim=0.f;
    for (int d=0;d<11;d++){
      float acc=bb[d];
      for (int k=0;k<11;k++) acc += irow[k]*bw[k*11+d];
      sim += tanh_(acc)*bc[d];
    }
    sb[t]=sim;
  }
  __syncthreads();
  if (t<64){
    float m=-1e30f;
    for (int q=0;q<8;q++) m=fmaxf(m, sm[q][hh]);
    float Z=0.f;
    for (int q=0;q<8;q++) Z+=__expf(sm[q][hh]-m);
    wgt[n][hh]=__expf(sm[n][hh]-m)/Z;
  }
  if (t<8){
    float m=-1e30f;
    for (int q=0;q<8;q++) m=fmaxf(m, sb[q]);
    float Z=0.f;
    for (int q=0;q<8;q++) Z+=__expf(sb[q]-m);
    wb_[t]=__expf(sb[t]-m)/Z;
  }
  __syncthreads();
  if (t<32){
    int hh2=t>>2;
    float acc=0.f;
    for (int q=0;q<8;q++) acc += wgt[q][hh2]* h[(size_t)(b*8+q)*HSTR + 267 + t];
    lb[11+t]=acc;
  }
  if (t<11){
    float acc=0.f;
    for (int q=0;q<8;q++) acc += wb_[q]* h[(size_t)(b*8+q)*HSTR + 256 + t];
    lb[t]=acc;
  }
  if (t<8) lb[43+t]=res[b*8+t];
  __syncthreads();
  float acc0=bia0f[t], acc1=bia0b[t];
  for (int k=0;k<51;k++){
    float v=lb[k];
    acc0 += v*w0f[t*51+k];
    acc1 += v*w0b[t*51+k];
  }
  float sc = gate_scale(t);
  xw[((size_t)t)*NBEAT + b]       = acc0*sc;
  xw[((size_t)(128+t))*NBEAT + b] = acc1*sc;
}

// ---------------- LSTM layer-1 input projection (transposed + pre-scaled out) ----------------
__global__ void k_xw(const float* inp, int din, const float* wf, const float* bf_,
                     const float* wb, const float* bb_, float* xw){
  int bid=blockIdx.x; int tt=bid>>1, dir=bid&1;
  const float* w = dir? wb:wf; const float* bia = dir? bb_:bf_;
  __shared__ float rowl[64];
  int t=threadIdx.x;   // 128 threads
  if (t<din) rowl[t]=inp[(size_t)tt*din+t];
  __syncthreads();
  float acc=bia[t];
  for (int k=0;k<din;k++) acc += rowl[k]*w[t*din+k];
  xw[((size_t)(dir*128 + t))*NBEAT + tt] = acc*gate_scale(t);
}

// ---------------- LSTM scan, latency-optimized ----------------
// One wave per direction, 2 blocks (one per CU -> each direction's 32KB whh
// slice fits that CU's 32KB L1; do NOT co-locate directions -- R8 lesson).
template<int DIR>
__device__ __forceinline__ void chunk8(int c, const float4& A0, const float4& A1,
    const float4& B0, const float4& B1,
    float* hu, float& creg, const float4* rA, const float4* rB,
    float cb1, float cb0, int l, float* out){
  float cxA[8] = {A0.x,A0.y,A0.z,A0.w,A1.x,A1.y,A1.z,A1.w};
  float cxB[8] = {B0.x,B0.y,B0.z,B0.w,B1.x,B1.y,B1.z,B1.w};
  float hst[8];
  #pragma unroll
  for (int u=0; u<8; u++){
    const int e = DIR ? (7-u) : u;
    float av[8], bv[8];
    #pragma unroll
    for (int q=0; q<8; q++){
      av[q] = hu[4*q+0]*rA[q].x + hu[4*q+1]*rA[q].y + hu[4*q+2]*rA[q].z + hu[4*q+3]*rA[q].w;
      bv[q] = hu[4*q+0]*rB[q].x + hu[4*q+1]*rB[q].y + hu[4*q+2]*rB[q].z + hu[4*q+3]*rB[q].w;
    }
    float accA = cxA[e] + (((av[0]+av[1])+(av[2]+av[3])) + ((av[4]+av[5])+(av[6]+av[7])));
    float accB = cxB[e] + (((bv[0]+bv[1])+(bv[2]+bv[3])) + ((bv[4]+bv[5])+(bv[6]+bv[7])));
    float pA  = frcp(1.f + fexp2(accA));            // sigm(i) low | sigm(f) high
    float rBv = frcp(1.f + fexp2(accB));
    float pB  = __builtin_fmaf(rBv, cb1, cb0);      // K2C*tanh(g) low | sigm(o) high
    float prod = pA * pB;                           // K2C*(i*g) in low lanes
    float prodIn = swap_lo_to_hi(prod);             // high lane l <- prod[l-32] (VALU)
    creg = __builtin_fmaf(pA, creg, prodIn);        // scaled c update (valid high lanes)
    float T = __builtin_fmaf(frcp(1.f + fexp2(creg)), 2.f, -1.f);  // tanh(c)
    float hnew = pB * T;                            // sigm(o)*tanh(c) (valid high lanes)
    hst[u] = hnew;
    #pragma unroll
    for (int d=0; d<32; d++)                        // broadcast h -> SGPRs for next step
      hu[d] = __uint_as_float(__builtin_amdgcn_readlane(__float_as_uint(hnew), 32+d));
  }
  if (l >= 32){
    int j = l - 32;
    #pragma unroll
    for (int u=0; u<8; u++){
      int s = c*8 + u;
      int tt = DIR ? (199 - s) : s;
      out[(size_t)tt*64 + DIR*32 + j] = hst[u];
    }
  }
}

template<int DIR>
__device__ __forceinline__ void lstm_scan(const float* xwT, const float* whh, float* out){
  const int l = threadIdx.x;
  const float sB = (l < 32) ? K2C : K1C;
  float4 rA[8], rB[8];
  #pragma unroll
  for (int q=0; q<8; q++){
    float4 a = *(const float4*)&whh[l*32 + q*4];
    float4 b = *(const float4*)&whh[(l+64)*32 + q*4];
    rA[q] = make_float4(a.x*K1C, a.y*K1C, a.z*K1C, a.w*K1C);
    rB[q] = make_float4(b.x*sB,  b.y*sB,  b.z*sB,  b.w*sB);
  }
  const float cb1 = (l < 32) ? (2.f*K2C) : 1.f;
  const float cb0 = (l < 32) ? (-K2C)    : 0.f;
  const float* xA = xwT + ((size_t)DIR*128 + l)*NBEAT;
  const float* xB = xwT + ((size_t)DIR*128 + 64 + l)*NBEAT;
  float hu[32];
  #pragma unroll
  for (int d=0; d<32; d++) hu[d] = 0.f;
  float creg = 0.f;
  float4 A0,A1,B0,B1, P0,P1,Q0,Q1;
#define LOADC(cidx, a0,a1,b0,b1) do {               \
    int _b = DIR ? (192 - (cidx)*8) : ((cidx)*8);   \
    a0 = *(const float4*)&xA[_b];                   \
    a1 = *(const float4*)&xA[_b+4];                 \
    b0 = *(const float4*)&xB[_b];                   \
    b1 = *(const float4*)&xB[_b+4];                 \
  } while(0)
  LOADC(0, A0,A1,B0,B1);
  for (int cc=0; cc<12; cc++){
    int c0 = 2*cc;
    LOADC(c0+1, P0,P1,Q0,Q1);
    chunk8<DIR>(c0,   A0,A1,B0,B1, hu, creg, rA, rB, cb1, cb0, l, out);
    LOADC(c0+2, A0,A1,B0,B1);
    chunk8<DIR>(c0+1, P0,P1,Q0,Q1, hu, creg, rA, rB, cb1, cb0, l, out);
  }
  chunk8<DIR>(24, A0,A1,B0,B1, hu, creg, rA, rB, cb1, cb0, l, out);
#undef LOADC
}

__global__ __launch_bounds__(64,1) void k_scan(const float* xwT, const float* whh_f,
                                               const float* whh_b, float* out){
  if (blockIdx.x == 0) lstm_scan<0>(xwT, whh_f, out);
  else                 lstm_scan<1>(xwT, whh_b, out);
}

// ---------------- fc head + final_out + h update (tempo fused) ----------------
__global__ void k_fc(float* ws, const int* bn, const float* w1, const float* b1,
                     const float* w2, const float* b2,
                     const float* wt, const float* bt, float* dout, int it){
  int i=blockIdx.x, t=threadIdx.x;   // 64 threads
  __shared__ float row[FINW];
  __shared__ float hid[32];
  __shared__ float fo[11];
  float* h=ws+OFF_H;
  int b = bn[i];
  const float* rnn = ws+OFF_RNN1;
  for (int c=t;c<FINW;c+=64){
    float v;
    if (c>=192 && c<256){ v=rnn[(size_t)b*64 + c-192]; h[(size_t)i*HSTR+c]=v; }
    else v=h[(size_t)i*HSTR+c];
    row[c]=v;
  }
  float tv = rnn[(size_t)b*64 + t]*wt[t];
  #pragma unroll
  for (int off=32; off; off>>=1) tv += __shfl_xor(tv, off, 64);
  __syncthreads();
  if (t<32){
    float acc=b1[t];
    for (int k=0;k<FINW;k++) acc += row[k]*w1[k*32+t];
    hid[t]=fmaxf(acc,0.f);
  }
  __syncthreads();
  if (t<10){
    float acc=b2[t];
    for (int m=0;m<32;m++) acc += hid[m]*w2[m*10+t];
    fo[1+t]=acc;
  }
  if (t==0) fo[0]=tv + bt[0];
  __syncthreads();
  if (t<11){
    float v=fo[t];
    h[(size_t)i*HSTR+256+t]=v;
    dout[(size_t)(2+it)*17600 + i*11 + t]=v;
    if (it==1) dout[i*11+t]=v;
  }
}

// ---------------- launcher ----------------
extern "C" void kernel_launch(void* const* d_in, const int* in_sizes, int n_in,
                              void* d_out, int out_size, void* d_ws, size_t ws_size,
                              hipStream_t stream){
  (void)in_sizes; (void)n_in; (void)out_size; (void)ws_size;
  float* ws=(float*)d_ws;
  const float* note    =(const float*)d_in[0];
  const float* pv      =(const float*)d_in[1];
  const float* res     =(const float*)d_in[2];
  const float* edges   =(const float*)d_in[3];
  const int*   bn      =(const int*)d_in[4];
  const float* w_style =(const float*)d_in[5];
  const float* b_style =(const float*)d_in[6];
  const float* w_init1 =(const float*)d_in[7];
  const float* b_init1 =(const float*)d_in[8];
  const float* w_init2 =(const float*)d_in[9];
  const float* b_init2 =(const float*)d_in[10];
  const float* gg_wa   =(const float*)d_in[11];
  const float* gg_ba   =(const float*)d_in[12];
  const float* gg_wz   =(const float*)d_in[13];
  const float* gg_wr   =(const float*)d_in[14];
  const float* gg_wh   =(const float*)d_in[15];
  const float* gg_uz   =(const float*)d_in[16];
  const float* gg_ur   =(const float*)d_in[17];
  const float* gg_uh   =(const float*)d_in[18];
  const float* abw     =(const float*)d_in[19];
  const float* abb     =(const float*)d_in[20];
  const float* abc     =(const float*)d_in[21];
  const float* amw     =(const float*)d_in[22];
  const float* amb     =(const float*)d_in[23];
  const float* amc     =(const float*)d_in[24];
  const float* wih0f   =(const float*)d_in[25];
  const float* whh0f   =(const float*)d_in[26];
  const float* b0f     =(const float*)d_in[27];
  const float* wih0b   =(const float*)d_in[28];
  const float* whh0b   =(const float*)d_in[29];
  const float* b0b     =(const float*)d_in[30];
  const float* wih1f   =(const float*)d_in[31];
  const float* whh1f   =(const float*)d_in[32];
  const float* b1f     =(const float*)d_in[33];
  const float* wih1b   =(const float*)d_in[34];
  const float* whh1b   =(const float*)d_in[35];
  const float* b1b     =(const float*)d_in[36];
  const float* w_tempo =(const float*)d_in[37];
  const float* b_tempo =(const float*)d_in[38];
  const float* w_fc1   =(const float*)d_in[39];
  const float* b_fc1   =(const float*)d_in[40];
  const float* w_fc2   =(const float*)d_in[41];
  const float* b_fc2   =(const float*)d_in[42];
  float* dout=(float*)d_out;

  hipMemsetAsync(ws+OFF_CUR, 0, NN*sizeof(int), stream);
  k_setup<<<NB_WA3+NB_INIT8+NB_SCAN,192,0,stream>>>(
      gg_wa,gg_ba,gg_wz,gg_wr,gg_wh,
      note,pv,w_style,b_style,w_init1,b_init1,w_init2,b_init2,
      edges,ws,dout);

  for (int it=0; it<2; it++){
    k_mstat<<<dim3(200,12),64,0,stream>>>(ws, it==0 ? 192 : 256);   // also emits M3(h0)
    k_agg_gru<<<NN,128,0,stream>>>(ws,gg_uz,gg_ur,gg_uh);           // g=0
    for (int g=1; g<3; g++){
      k_m3dyn<<<dim3(200,12),64,0,stream>>>(ws);
      k_agg_gru<<<NN,128,0,stream>>>(ws,gg_uz,gg_ur,gg_uh);
    }
    k_attn_xw<<<NBEAT,128,0,stream>>>(ws,amw,amb,amc,abw,abb,abc,res,
                                      wih0f,b0f,wih0b,b0b,ws+OFF_XW);
    k_scan<<<2,64,0,stream>>>(ws+OFF_XW,whh0f,whh0b,ws+OFF_RNN0);
    k_xw<<<2*NBEAT,128,0,stream>>>(ws+OFF_RNN0,64,wih1f,b1f,wih1b,b1b,ws+OFF_XW);
    k_scan<<<2,64,0,stream>>>(ws+OFF_XW,whh1f,whh1b,ws+OFF_RNN1);
    k_fc<<<NN,64,0,stream>>>(ws,bn,w_fc1,b_fc1,w_fc2,b_fc2,w_tempo,b_tempo,dout,it);
  }
}

// Round 10
// 733.194 us; speedup vs baseline: 2.8869x; 1.0105x over previous
//
#include <hip/hip_runtime.h>
#include <stdint.h>

// ---------------- problem constants ----------------
#define NN     1600
#define NBEAT  200
#define FINW   299
#define HSTR   300      // padded row stride for h
#define SECW   43
#define EDG    12
#define C3     129      // 3*43 projected width
#define CM     128      // main columns (129th handled separately)
#define DEG_CAP 256     // per-destination adjacency bucket (mean 77, max~112)

// fused-setup block ranges (all 192-thread blocks). ROLES FIRST (R2 config --
// best measured). R3's exact-residency grid did NOT speed the scan; R6/R7 grid
// barriers cost ~160us each at 1024 blocks; R8 single-CU beat fusion thrashes
// L1 (64KB whh working set vs 32KB L1). This launch structure is the proven one.
#define NB_WA3   450
#define NB_INIT8 200
#define NB_SCAN  2560

// exp2/rcp-based fast activations: -log2e and -2*log2e scales folded in.
#define K1C (-1.4426950408889634f)
#define K2C (-2.8853900817779268f)

#if __has_builtin(__builtin_amdgcn_exp2f)
__device__ __forceinline__ float fexp2(float x){ return __builtin_amdgcn_exp2f(x); }
#else
__device__ __forceinline__ float fexp2(float x){ return exp2f(x); }
#endif
#if __has_builtin(__builtin_amdgcn_rcpf)
__device__ __forceinline__ float frcp(float x){ return __builtin_amdgcn_rcpf(x); }
#else
__device__ __forceinline__ float frcp(float x){ return 1.0f/x; }
#endif

__device__ __forceinline__ float sigm(float x){ return frcp(1.f + fexp2(K1C*x)); }
__device__ __forceinline__ float tanh_(float x){ return __builtin_fmaf(frcp(1.f + fexp2(K2C*x)), 2.f, -1.f); }

// gate column -> activation input scale (i,f,o sigmoid: K1C; g tanh: K2C)
__device__ __forceinline__ float gate_scale(int col){
  return (col >= 64 && col < 96) ? K2C : K1C;
}

// high lane l receives v from lane l-32 (VALU permlane, no lgkm wait on the
// serial LSTM chain). r[0] high lane l = v[l-32]  (verified R5; R4 bug was r[1]).
__device__ __forceinline__ float swap_lo_to_hi(float v){
#if __has_builtin(__builtin_amdgcn_permlane32_swap)
  typedef unsigned u32x2 __attribute__((ext_vector_type(2)));
  u32x2 r = __builtin_amdgcn_permlane32_swap(__float_as_uint(v), __float_as_uint(v), false, false);
  return __uint_as_float(r[0]);
#else
  return __shfl(v, (int)(threadIdx.x & 31), 64);
#endif
}

// ---------------- workspace layout (4-byte words) ----------------
constexpr size_t OFF_H    = 0;                                   // 1600*300
constexpr size_t OFF_WA3  = OFF_H    + (size_t)NN*HSTR;          // 12*299*128
constexpr size_t OFF_WA3X = OFF_WA3  + (size_t)EDG*FINW*CM;      // 12*299
constexpr size_t OFF_B3   = OFF_WA3X + (size_t)EDG*FINW;         // 132
constexpr size_t OFF_MST  = OFF_B3   + 132;                      // 12*1600*128
constexpr size_t OFF_MSTX = OFF_MST  + (size_t)EDG*NN*CM;        // 12*1600
constexpr size_t OFF_M3   = OFF_MSTX + (size_t)EDG*NN;           // 12*1600*128
constexpr size_t OFF_M3X  = OFF_M3   + (size_t)EDG*NN*CM;        // 12*1600
constexpr size_t OFF_CUR  = OFF_M3X  + (size_t)EDG*NN;           // 1600 ints
constexpr size_t OFF_ADJR = OFF_CUR  + NN;                       // 1600*256 ints
constexpr size_t OFF_XW   = OFF_ADJR + (size_t)NN*DEG_CAP;       // 2*128*200 (TRANSPOSED: [dir*128+col][beat])
constexpr size_t OFF_RNN0 = OFF_XW   + (size_t)2*NBEAT*128;      // 200*64
constexpr size_t OFF_RNN1 = OFF_RNN0 + (size_t)NBEAT*64;         // 200*64

// ---------------- fused setup: wa3(8-row GEMM) | init8 | adj-scan (one dispatch) ----------------
// Single manually-unioned LDS buffer: 2392 floats = 9568 B keeps 10 blocks/CU.
__global__ __launch_bounds__(192) void k_setup(
    const float* wa, const float* ba, const float* wz, const float* wr, const float* wh,
    const float* note, const float* pv, const float* w_style, const float* b_style,
    const float* w1, const float* b1, const float* w2, const float* b2,
    const float* edges, float* ws, float* dout){
  int blk = blockIdx.x;
  int t = threadIdx.x;
  __shared__ __align__(16) float smem[2392];
  if (blk < NB_WA3){
    // ---- wa3 as blocked GEMM: 8 rows of [3588x299]@[299x129] per block.
    float* lrow = smem;            // 299*8 = 2392 floats
    int base = blk*8;              // row base in [0,3600); row 3588 = ba; 3589+ skipped
    for (int x=t; x<8*299; x+=192){
      int r = x & 7, s = x >> 3;
      int R = base + r;
      float v = 0.f;
      if (R < 3588)       v = wa[(size_t)R*FINW + s];
      else if (R == 3588) v = ba[s];
      lrow[s*8 + r] = v;
    }
    __syncthreads();
    if (t < C3){
      const float* Wp; int cc;
      if (t<43){Wp=wz; cc=t;} else if (t<86){Wp=wr; cc=t-43;} else {Wp=wh; cc=t-86;}
      float acc[8];
      #pragma unroll
      for (int r=0;r<8;r++) acc[r]=0.f;
      for (int s=0;s<FINW;s++){
        float w = Wp[s*43+cc];
        float4 lo = *(const float4*)&lrow[s*8];
        float4 hi = *(const float4*)&lrow[s*8+4];
        acc[0]+=lo.x*w; acc[1]+=lo.y*w; acc[2]+=lo.z*w; acc[3]+=lo.w*w;
        acc[4]+=hi.x*w; acc[5]+=hi.y*w; acc[6]+=hi.z*w; acc[7]+=hi.w*w;
      }
      #pragma unroll
      for (int r=0;r<8;r++){
        int R = base + r;
        if (R < 3588){
          if (t<CM) ws[OFF_WA3 + (size_t)R*CM + t] = acc[r];
          else      ws[OFF_WA3X + R]               = acc[r];
        } else if (R == 3588){
          ws[OFF_B3 + t] = acc[r];
        }
      }
    }
  } else if (blk < NB_WA3 + NB_INIT8){
    // ---- init8: 8 notes per block, wa3-style weight amortization.
    float* ln    = smem;           // 128*8 = 1024
    float* lh1   = smem + 1024;    // 64*8  = 512
    float* lo    = smem + 1536;    // 8*11  = 88
    float* lperf = smem + 1624;    // 64
    int i0 = (blk - NB_WA3)*8;
    for (int x=t; x<8*128; x+=192){
      int r = x >> 7, k = x & 127;
      ln[k*8 + r] = note[(size_t)(i0+r)*128 + k];
    }
    if (t>=64 && t<128){
      int u=t-64;
      float acc=b_style[u];
      for (int k=0;k<16;k++) acc += pv[k]*w_style[k*64+u];
      lperf[u]=fmaxf(acc,0.f);
    }
    __syncthreads();
    if (t<64){
      float acc[8];
      #pragma unroll
      for (int r=0;r<8;r++) acc[r]=b1[t];
      for (int k=0;k<128;k++){
        float w = w1[k*64+t];
        float4 a = *(const float4*)&ln[k*8];
        float4 b = *(const float4*)&ln[k*8+4];
        acc[0]+=a.x*w; acc[1]+=a.y*w; acc[2]+=a.z*w; acc[3]+=a.w*w;
        acc[4]+=b.x*w; acc[5]+=b.y*w; acc[6]+=b.z*w; acc[7]+=b.w*w;
      }
      #pragma unroll
      for (int r=0;r<8;r++) lh1[t*8+r]=fmaxf(acc[r],0.f);
    }
    __syncthreads();
    if (t<88){
      int r = t & 7, c = t >> 3;   // c in [0,11)
      float acc=b2[c];
      for (int k=0;k<64;k++) acc += lh1[k*8+r]*w2[k*11+c];
      lo[r*11+c]=acc;
      dout[17600 + (size_t)(i0+r)*11 + c] = acc;
    }
    __syncthreads();
    #pragma unroll
    for (int r=0;r<8;r++){
      for (int c=t;c<FINW;c+=192){
        float v;
        if (c<128)      v=ln[c*8+r];
        else if (c<192) v=lperf[c-128];
        else if (c<256) v=0.f;
        else if (c<267) v=lo[r*11+(c-256)];
        else            v=0.f;
        ws[OFF_H + (size_t)(i0+r)*HSTR + c]=v;
      }
    }
  } else {
    // ---- adj: sparse edge extraction into fixed-width buckets.
    // 8-deep load batching (R9: 4-deep ran at 1.75 TB/s with no pipe saturated
    // -> MLP-limited hypothesis; 8 outstanding uint4/thread doubles bytes in
    // flight at ~same instruction overhead; ~48 live VGPRs stays under the
    // 64-VGPR cliff for 10 blocks/CU).
    int* cur  = (int*)(ws + OFF_CUR);
    int* adjr = (int*)(ws + OFF_ADJR);
    const uint4* p = (const uint4*)edges;
    const unsigned int nvec = 7680000u;   // 12*1600*1600/4
    const unsigned int stride = (unsigned int)NB_SCAN*192u;
    unsigned int v0 = (unsigned int)(blk - NB_WA3 - NB_INIT8)*192u + t;
    for (unsigned int b0 = v0; b0 < nvec; b0 += 8u*stride){
      uint4 wv[8];
      unsigned int vv[8];
      #pragma unroll
      for (int u=0; u<8; u++){
        unsigned int v = b0 + (unsigned int)u*stride;
        vv[u] = v;
        wv[u] = (v < nvec) ? p[v] : make_uint4(0,0,0,0);
      }
      #pragma unroll
      for (int u=0; u<8; u++){
        uint4 w = wv[u];
        if ((w.x|w.y|w.z|w.w)==0u) continue;
        unsigned int base = vv[u]*4u;
        unsigned int arr[4]={w.x,w.y,w.z,w.w};
        #pragma unroll
        for (int q=0;q<4;q++){
          if (arr[q]){
            unsigned int idx=base+q;
            unsigned int j=idx%1600u;
            int slot=atomicAdd(&cur[j],1);
            if (slot<DEG_CAP) adjr[j*DEG_CAP + slot]=(int)(idx/1600u);  // row = e*1600+i
          }
        }
      }
    }
  }
}

// ---------------- static message part + M3(h0) (once per seq-iter) ----------------
// Incremental form: accumulates h cols [dlo, dmain) into MST/MSTX.
//   it=0: dlo=0,   dmain=192 (rnn cols are exactly zero), acc starts at 0 -> full rewrite.
//   it=1: dlo=192, dmain=256, acc starts from stored MST  -> only rnn cols re-read (70% less
//         weight traffic, SAME proven 8-row geometry -- R3's 16-row variant regressed).
// Rep-safe: every launch sequence begins with the it=0 full rewrite.
__global__ void k_mstat(float* ws, int dlo, int dmain){
  int e = blockIdx.y; int i0 = blockIdx.x*8;
  int t = threadIdx.x;
  __shared__ float lh[8][256];
  __shared__ float lh2[8][44];
  const float* h = ws + OFF_H;
  for (int x=t; x<512; x+=64){
    int r = x>>6, dq = x&63;
    ((float4*)&lh[r][0])[dq] = ((const float4*)(h + (size_t)(i0+r)*HSTR))[dq];
  }
  for (int x=t; x<88; x+=64){
    int r = x/11, dq = x-r*11;
    ((float4*)&lh2[r][0])[dq] = ((const float4*)(h + (size_t)(i0+r)*HSTR + 256))[dq];
  }
  __syncthreads();
  const float* wm = ws + OFF_WA3 + (size_t)e*FINW*CM;
  int c0 = 2*t;
  float* mst = ws + OFF_MST + ((size_t)e*NN + i0)*CM;
  float acc[8][2];
  if (dlo == 0){
    #pragma unroll
    for (int r=0;r<8;r++){acc[r][0]=0.f;acc[r][1]=0.f;}
  } else {
    #pragma unroll
    for (int r=0;r<8;r++){
      float2 m = *(const float2*)(mst + (size_t)r*CM + c0);
      acc[r][0]=m.x; acc[r][1]=m.y;
    }
  }
  for (int d=dlo; d<dmain; d+=4){
    float4 hv[8];
    #pragma unroll
    for (int r=0;r<8;r++) hv[r] = *(const float4*)&lh[r][d];
    #pragma unroll
    for (int dd=0;dd<4;dd++){
      float2 w = *(const float2*)(wm + (size_t)(d+dd)*CM + c0);
      #pragma unroll
      for (int r=0;r<8;r++){
        float hvv = ((const float*)&hv[r])[dd];
        acc[r][0] += hvv*w.x; acc[r][1] += hvv*w.y;
      }
    }
  }
  #pragma unroll
  for (int r=0;r<8;r++) *(float2*)(mst + (size_t)r*CM + c0) = make_float2(acc[r][0],acc[r][1]);
  // continue over dynamic cols 256..298 -> M3 = mst + hs@wd
  const float* wd = wm + (size_t)256*CM;
  for (int d=0; d<SECW; d++){
    float2 w = *(const float2*)(wd + (size_t)d*CM + c0);
    #pragma unroll
    for (int r=0;r<8;r++){
      float hvv = lh2[r][d];
      acc[r][0] += hvv*w.x; acc[r][1] += hvv*w.y;
    }
  }
  float* m3 = ws + OFF_M3 + ((size_t)e*NN + i0)*CM;
  #pragma unroll
  for (int r=0;r<8;r++) *(float2*)(m3 + (size_t)r*CM + c0) = make_float2(acc[r][0],acc[r][1]);
  if (t<8){
    const float* wx = ws + OFF_WA3X + (size_t)e*FINW;
    float a = (dlo == 0) ? 0.f : ws[OFF_MSTX + (size_t)e*NN + i0 + t];
    for (int d=dlo; d<dmain; d++) a += lh[t][d]*wx[d];
    ws[OFF_MSTX + (size_t)e*NN + i0 + t] = a;
    for (int d=0; d<SECW; d++) a += lh2[t][d]*wx[256+d];
    ws[OFF_M3X + (size_t)e*NN + i0 + t] = a;
  }
}

// ---------------- M3 recompute (g>=1) ----------------
__global__ void k_m3dyn(float* ws){
  int e=blockIdx.y, i0=blockIdx.x*8, t=threadIdx.x;
  __shared__ float lhs[8][44];
  const float* h = ws + OFF_H;
  for (int x=t; x<8*43; x+=64){ int r=x/43, d=x-r*43; lhs[r][d]=h[(size_t)(i0+r)*HSTR+256+d]; }
  __syncthreads();
  const float* wd  = ws + OFF_WA3 + ((size_t)e*FINW+256)*CM;
  const float* mst = ws + OFF_MST + ((size_t)e*NN+i0)*CM;
  int c0=2*t;
  float acc[8][2];
  #pragma unroll
  for (int r=0;r<8;r++){ float2 m=*(const float2*)(mst+(size_t)r*CM+c0); acc[r][0]=m.x; acc[r][1]=m.y; }
  for (int d=0; d<43; d++){
    float2 w=*(const float2*)(wd + (size_t)d*CM + c0);
    #pragma unroll
    for (int r=0;r<8;r++){ float hv=lhs[r][d]; acc[r][0]+=hv*w.x; acc[r][1]+=hv*w.y; }
  }
  float* m3 = ws + OFF_M3 + ((size_t)e*NN+i0)*CM;
  #pragma unroll
  for (int r=0;r<8;r++) *(float2*)(m3+(size_t)r*CM+c0)=make_float2(acc[r][0],acc[r][1]);
  if (t<8){
    float a = ws[OFF_MSTX + (size_t)e*NN+i0+t];
    const float* wx = ws + OFF_WA3X + (size_t)e*FINW + 256;
    for (int d=0;d<43;d++) a += lhs[t][d]*wx[d];
    ws[OFF_M3X + (size_t)e*NN+i0+t]=a;
  }
}

// gather (LDS-staged adjacency + 8 independent accumulators) + GRU update
__global__ void k_agg_gru(float* ws, const float* uz, const float* ur, const float* uh){
  int j=blockIdx.x, t=threadIdx.x;   // 128 threads
  __shared__ float lpre[C3];
  __shared__ float lhs[SECW];
  __shared__ float lrh[SECW];
  __shared__ int   ladj[DEG_CAP];
  float* h = ws + OFF_H;
  const int* cur =(const int*)(ws+OFF_CUR);
  const int* adjr=(const int*)(ws+OFF_ADJR) + (size_t)j*DEG_CAP;
  int cnt = cur[j]; if (cnt>DEG_CAP) cnt=DEG_CAP;
  for (int k=t;k<cnt;k+=128) ladj[k]=adjr[k];
  if (t<SECW) lhs[t] = h[(size_t)j*HSTR + 256 + t];
  __syncthreads();
  const float* M3=ws+OFF_M3; const float* M3X=ws+OFF_M3X;
  float a0 = ws[OFF_B3 + t];
  float ax = (t==0)? ws[OFF_B3+128] : 0.f;
  float p1=0.f,p2=0.f,p3=0.f,p4=0.f,p5=0.f,p6=0.f,p7=0.f;
  int k=0;
  for (; k+8<=cnt; k+=8){
    int r0=ladj[k],r1=ladj[k+1],r2=ladj[k+2],r3=ladj[k+3];
    int r4=ladj[k+4],r5=ladj[k+5],r6=ladj[k+6],r7=ladj[k+7];
    a0 += M3[(size_t)r0*CM+t];
    p1 += M3[(size_t)r1*CM+t];
    p2 += M3[(size_t)r2*CM+t];
    p3 += M3[(size_t)r3*CM+t];
    p4 += M3[(size_t)r4*CM+t];
    p5 += M3[(size_t)r5*CM+t];
    p6 += M3[(size_t)r6*CM+t];
    p7 += M3[(size_t)r7*CM+t];
    if (t==0) ax += ((M3X[r0]+M3X[r1])+(M3X[r2]+M3X[r3]))
                  + ((M3X[r4]+M3X[r5])+(M3X[r6]+M3X[r7]));
  }
  for (; k<cnt; k++){ int r=ladj[k]; a0+=M3[(size_t)r*CM+t]; if(t==0) ax+=M3X[r]; }
  a0 += ((p1+p2)+(p3+p4)) + ((p5+p6)+p7);
  lpre[t]=a0; if (t==0) lpre[128]=ax;
  __syncthreads();
  float z=0.f;
  if (t<SECW){
    float az=lpre[t], ar=lpre[43+t];
    for (int d=0;d<SECW;d++){ float hv=lhs[d]; az+=hv*uz[d*43+t]; ar+=hv*ur[d*43+t]; }
    z=sigm(az);
    float r=sigm(ar);
    lrh[t]=r*lhs[t];
  }
  __syncthreads();
  if (t<SECW){
    float ah=lpre[86+t];
    for (int d=0;d<SECW;d++) ah += lrh[d]*uh[d*43+t];
    float cand=tanh_(ah);
    h[(size_t)j*HSTR+256+t] = (1.f-z)*lhs[t] + z*cand;
  }
}

// ---------------- beat attention + layer-0 LSTM input projection (fused) ----------------
// xw written TRANSPOSED ([dir*128+col]*NBEAT + beat) and PRE-SCALED.
__global__ void k_attn_xw(float* ws, const float* mw, const float* mb, const float* mc,
                          const float* bw, const float* bb, const float* bc,
                          const float* res,
                          const float* w0f, const float* bia0f,
                          const float* w0b, const float* bia0b, float* xw){
  int b=blockIdx.x, t=threadIdx.x;  // 128 threads
  float* h=ws+OFF_H;
  __shared__ float sm[8][8];
  __shared__ float wgt[8][8];
  __shared__ float sb[8];
  __shared__ float wb_[8];
  __shared__ float lb[52];
  int n=t>>3, hh=t&7;
  if (t<64){
    const float* mrow = h + (size_t)(b*8+n)*HSTR + 267;
    float sim=0.f;
    for (int d=0;d<4;d++){
      int c=hh*4+d;
      float acc=mb[c];
      for (int k=0;k<32;k++) acc += mrow[k]*mw[k*32+c];
      sim += tanh_(acc)*mc[c];
    }
    sm[n][hh]=sim;
  }
  if (t<8){
    const float* irow = h + (size_t)(b*8+t)*HSTR + 256;
    float sim=0.f;
    for (int d=0;d<11;d++){
      float acc=bb[d];
      for (int k=0;k<11;k++) acc += irow[k]*bw[k*11+d];
      sim += tanh_(acc)*bc[d];
    }
    sb[t]=sim;
  }
  __syncthreads();
  if (t<64){
    float m=-1e30f;
    for (int q=0;q<8;q++) m=fmaxf(m, sm[q][hh]);
    float Z=0.f;
    for (int q=0;q<8;q++) Z+=__expf(sm[q][hh]-m);
    wgt[n][hh]=__expf(sm[n][hh]-m)/Z;
  }
  if (t<8){
    float m=-1e30f;
    for (int q=0;q<8;q++) m=fmaxf(m, sb[q]);
    float Z=0.f;
    for (int q=0;q<8;q++) Z+=__expf(sb[q]-m);
    wb_[t]=__expf(sb[t]-m)/Z;
  }
  __syncthreads();
  if (t<32){
    int hh2=t>>2;
    float acc=0.f;
    for (int q=0;q<8;q++) acc += wgt[q][hh2]* h[(size_t)(b*8+q)*HSTR + 267 + t];
    lb[11+t]=acc;
  }
  if (t<11){
    float acc=0.f;
    for (int q=0;q<8;q++) acc += wb_[q]* h[(size_t)(b*8+q)*HSTR + 256 + t];
    lb[t]=acc;
  }
  if (t<8) lb[43+t]=res[b*8+t];
  __syncthreads();
  float acc0=bia0f[t], acc1=bia0b[t];
  for (int k=0;k<51;k++){
    float v=lb[k];
    acc0 += v*w0f[t*51+k];
    acc1 += v*w0b[t*51+k];
  }
  float sc = gate_scale(t);
  xw[((size_t)t)*NBEAT + b]       = acc0*sc;
  xw[((size_t)(128+t))*NBEAT + b] = acc1*sc;
}

// ---------------- LSTM layer-1 input projection (transposed + pre-scaled out) ----------------
__global__ void k_xw(const float* inp, int din, const float* wf, const float* bf_,
                     const float* wb, const float* bb_, float* xw){
  int bid=blockIdx.x; int tt=bid>>1, dir=bid&1;
  const float* w = dir? wb:wf; const float* bia = dir? bb_:bf_;
  __shared__ float rowl[64];
  int t=threadIdx.x;   // 128 threads
  if (t<din) rowl[t]=inp[(size_t)tt*din+t];
  __syncthreads();
  float acc=bia[t];
  for (int k=0;k<din;k++) acc += rowl[k]*w[t*din+k];
  xw[((size_t)(dir*128 + t))*NBEAT + tt] = acc*gate_scale(t);
}

// ---------------- LSTM scan, latency-optimized ----------------
// One wave per direction, 2 blocks (one per CU -> each direction's 32KB whh
// slice fits that CU's 32KB L1; do NOT co-locate directions -- R8 lesson).
template<int DIR>
__device__ __forceinline__ void chunk8(int c, const float4& A0, const float4& A1,
    const float4& B0, const float4& B1,
    float* hu, float& creg, const float4* rA, const float4* rB,
    float cb1, float cb0, int l, float* out){
  float cxA[8] = {A0.x,A0.y,A0.z,A0.w,A1.x,A1.y,A1.z,A1.w};
  float cxB[8] = {B0.x,B0.y,B0.z,B0.w,B1.x,B1.y,B1.z,B1.w};
  float hst[8];
  #pragma unroll
  for (int u=0; u<8; u++){
    const int e = DIR ? (7-u) : u;
    float av[8], bv[8];
    #pragma unroll
    for (int q=0; q<8; q++){
      av[q] = hu[4*q+0]*rA[q].x + hu[4*q+1]*rA[q].y + hu[4*q+2]*rA[q].z + hu[4*q+3]*rA[q].w;
      bv[q] = hu[4*q+0]*rB[q].x + hu[4*q+1]*rB[q].y + hu[4*q+2]*rB[q].z + hu[4*q+3]*rB[q].w;
    }
    float accA = cxA[e] + (((av[0]+av[1])+(av[2]+av[3])) + ((av[4]+av[5])+(av[6]+av[7])));
    float accB = cxB[e] + (((bv[0]+bv[1])+(bv[2]+bv[3])) + ((bv[4]+bv[5])+(bv[6]+bv[7])));
    float pA  = frcp(1.f + fexp2(accA));            // sigm(i) low | sigm(f) high
    float rBv = frcp(1.f + fexp2(accB));
    float pB  = __builtin_fmaf(rBv, cb1, cb0);      // K2C*tanh(g) low | sigm(o) high
    float prod = pA * pB;                           // K2C*(i*g) in low lanes
    float prodIn = swap_lo_to_hi(prod);             // high lane l <- prod[l-32] (VALU)
    creg = __builtin_fmaf(pA, creg, prodIn);        // scaled c update (valid high lanes)
    float T = __builtin_fmaf(frcp(1.f + fexp2(creg)), 2.f, -1.f);  // tanh(c)
    float hnew = pB * T;                            // sigm(o)*tanh(c) (valid high lanes)
    hst[u] = hnew;
    #pragma unroll
    for (int d=0; d<32; d++)                        // broadcast h -> SGPRs for next step
      hu[d] = __uint_as_float(__builtin_amdgcn_readlane(__float_as_uint(hnew), 32+d));
  }
  if (l >= 32){
    int j = l - 32;
    #pragma unroll
    for (int u=0; u<8; u++){
      int s = c*8 + u;
      int tt = DIR ? (199 - s) : s;
      out[(size_t)tt*64 + DIR*32 + j] = hst[u];
    }
  }
}

template<int DIR>
__device__ __forceinline__ void lstm_scan(const float* xwT, const float* whh, float* out){
  const int l = threadIdx.x;
  const float sB = (l < 32) ? K2C : K1C;
  float4 rA[8], rB[8];
  #pragma unroll
  for (int q=0; q<8; q++){
    float4 a = *(const float4*)&whh[l*32 + q*4];
    float4 b = *(const float4*)&whh[(l+64)*32 + q*4];
    rA[q] = make_float4(a.x*K1C, a.y*K1C, a.z*K1C, a.w*K1C);
    rB[q] = make_float4(b.x*sB,  b.y*sB,  b.z*sB,  b.w*sB);
  }
  const float cb1 = (l < 32) ? (2.f*K2C) : 1.f;
  const float cb0 = (l < 32) ? (-K2C)    : 0.f;
  const float* xA = xwT + ((size_t)DIR*128 + l)*NBEAT;
  const float* xB = xwT + ((size_t)DIR*128 + 64 + l)*NBEAT;
  float hu[32];
  #pragma unroll
  for (int d=0; d<32; d++) hu[d] = 0.f;
  float creg = 0.f;
  float4 A0,A1,B0,B1, P0,P1,Q0,Q1;
#define LOADC(cidx, a0,a1,b0,b1) do {               \
    int _b = DIR ? (192 - (cidx)*8) : ((cidx)*8);   \
    a0 = *(const float4*)&xA[_b];                   \
    a1 = *(const float4*)&xA[_b+4];                 \
    b0 = *(const float4*)&xB[_b];                   \
    b1 = *(const float4*)&xB[_b+4];                 \
  } while(0)
  LOADC(0, A0,A1,B0,B1);
  for (int cc=0; cc<12; cc++){
    int c0 = 2*cc;
    LOADC(c0+1, P0,P1,Q0,Q1);
    chunk8<DIR>(c0,   A0,A1,B0,B1, hu, creg, rA, rB, cb1, cb0, l, out);
    LOADC(c0+2, A0,A1,B0,B1);
    chunk8<DIR>(c0+1, P0,P1,Q0,Q1, hu, creg, rA, rB, cb1, cb0, l, out);
  }
  chunk8<DIR>(24, A0,A1,B0,B1, hu, creg, rA, rB, cb1, cb0, l, out);
#undef LOADC
}

__global__ __launch_bounds__(64,1) void k_scan(const float* xwT, const float* whh_f,
                                               const float* whh_b, float* out){
  if (blockIdx.x == 0) lstm_scan<0>(xwT, whh_f, out);
  else                 lstm_scan<1>(xwT, whh_b, out);
}

// ---------------- fc head + final_out + h update (tempo fused) ----------------
__global__ void k_fc(float* ws, const int* bn, const float* w1, const float* b1,
                     const float* w2, const float* b2,
                     const float* wt, const float* bt, float* dout, int it){
  int i=blockIdx.x, t=threadIdx.x;   // 64 threads
  __shared__ float row[FINW];
  __shared__ float hid[32];
  __shared__ float fo[11];
  float* h=ws+OFF_H;
  int b = bn[i];
  const float* rnn = ws+OFF_RNN1;
  for (int c=t;c<FINW;c+=64){
    float v;
    if (c>=192 && c<256){ v=rnn[(size_t)b*64 + c-192]; h[(size_t)i*HSTR+c]=v; }
    else v=h[(size_t)i*HSTR+c];
    row[c]=v;
  }
  float tv = rnn[(size_t)b*64 + t]*wt[t];
  #pragma unroll
  for (int off=32; off; off>>=1) tv += __shfl_xor(tv, off, 64);
  __syncthreads();
  if (t<32){
    float acc=b1[t];
    for (int k=0;k<FINW;k++) acc += row[k]*w1[k*32+t];
    hid[t]=fmaxf(acc,0.f);
  }
  __syncthreads();
  if (t<10){
    float acc=b2[t];
    for (int m=0;m<32;m++) acc += hid[m]*w2[m*10+t];
    fo[1+t]=acc;
  }
  if (t==0) fo[0]=tv + bt[0];
  __syncthreads();
  if (t<11){
    float v=fo[t];
    h[(size_t)i*HSTR+256+t]=v;
    dout[(size_t)(2+it)*17600 + i*11 + t]=v;
    if (it==1) dout[i*11+t]=v;
  }
}

// ---------------- launcher ----------------
extern "C" void kernel_launch(void* const* d_in, const int* in_sizes, int n_in,
                              void* d_out, int out_size, void* d_ws, size_t ws_size,
                              hipStream_t stream){
  (void)in_sizes; (void)n_in; (void)out_size; (void)ws_size;
  float* ws=(float*)d_ws;
  const float* note    =(const float*)d_in[0];
  const float* pv      =(const float*)d_in[1];
  const float* res     =(const float*)d_in[2];
  const float* edges   =(const float*)d_in[3];
  const int*   bn      =(const int*)d_in[4];
  const float* w_style =(const float*)d_in[5];
  const float* b_style =(const float*)d_in[6];
  const float* w_init1 =(const float*)d_in[7];
  const float* b_init1 =(const float*)d_in[8];
  const float* w_init2 =(const float*)d_in[9];
  const float* b_init2 =(const float*)d_in[10];
  const float* gg_wa   =(const float*)d_in[11];
  const float* gg_ba   =(const float*)d_in[12];
  const float* gg_wz   =(const float*)d_in[13];
  const float* gg_wr   =(const float*)d_in[14];
  const float* gg_wh   =(const float*)d_in[15];
  const float* gg_uz   =(const float*)d_in[16];
  const float* gg_ur   =(const float*)d_in[17];
  const float* gg_uh   =(const float*)d_in[18];
  const float* abw     =(const float*)d_in[19];
  const float* abb     =(const float*)d_in[20];
  const float* abc     =(const float*)d_in[21];
  const float* amw     =(const float*)d_in[22];
  const float* amb     =(const float*)d_in[23];
  const float* amc     =(const float*)d_in[24];
  const float* wih0f   =(const float*)d_in[25];
  const float* whh0f   =(const float*)d_in[26];
  const float* b0f     =(const float*)d_in[27];
  const float* wih0b   =(const float*)d_in[28];
  const float* whh0b   =(const float*)d_in[29];
  const float* b0b     =(const float*)d_in[30];
  const float* wih1f   =(const float*)d_in[31];
  const float* whh1f   =(const float*)d_in[32];
  const float* b1f     =(const float*)d_in[33];
  const float* wih1b   =(const float*)d_in[34];
  const float* whh1b   =(const float*)d_in[35];
  const float* b1b     =(const float*)d_in[36];
  const float* w_tempo =(const float*)d_in[37];
  const float* b_tempo =(const float*)d_in[38];
  const float* w_fc1   =(const float*)d_in[39];
  const float* b_fc1   =(const float*)d_in[40];
  const float* w_fc2   =(const float*)d_in[41];
  const float* b_fc2   =(const float*)d_in[42];
  float* dout=(float*)d_out;

  hipMemsetAsync(ws+OFF_CUR, 0, NN*sizeof(int), stream);
  k_setup<<<NB_WA3+NB_INIT8+NB_SCAN,192,0,stream>>>(
      gg_wa,gg_ba,gg_wz,gg_wr,gg_wh,
      note,pv,w_style,b_style,w_init1,b_init1,w_init2,b_init2,
      edges,ws,dout);

  for (int it=0; it<2; it++){
    // it=0: full static rewrite (cols 0..191; rnn cols are zero).
    // it=1: incremental -- only rnn cols 192..255 on top of stored MST.
    if (it==0) k_mstat<<<dim3(200,12),64,0,stream>>>(ws, 0, 192);
    else       k_mstat<<<dim3(200,12),64,0,stream>>>(ws, 192, 256);
    k_agg_gru<<<NN,128,0,stream>>>(ws,gg_uz,gg_ur,gg_uh);           // g=0
    for (int g=1; g<3; g++){
      k_m3dyn<<<dim3(200,12),64,0,stream>>>(ws);
      k_agg_gru<<<NN,128,0,stream>>>(ws,gg_uz,gg_ur,gg_uh);
    }
    k_attn_xw<<<NBEAT,128,0,stream>>>(ws,amw,amb,amc,abw,abb,abc,res,
                                      wih0f,b0f,wih0b,b0b,ws+OFF_XW);
    k_scan<<<2,64,0,stream>>>(ws+OFF_XW,whh0f,whh0b,ws+OFF_RNN0);
    k_xw<<<2*NBEAT,128,0,stream>>>(ws+OFF_RNN0,64,wih1f,b1f,wih1b,b1b,ws+OFF_XW);
    k_scan<<<2,64,0,stream>>>(ws+OFF_XW,whh1f,whh1b,ws+OFF_RNN1);
    k_fc<<<NN,64,0,stream>>>(ws,bn,w_fc1,b_fc1,w_fc2,b_fc2,w_tempo,b_tempo,dout,it);
  }
}